// Round 7
// baseline (384.645 us; speedup 1.0000x reference)
//
#include <hip/hip_runtime.h>
#include <math.h>

// ---------------------------------------------------------------------------
// Problem constants
// ---------------------------------------------------------------------------
#define N_SEQ   896
#define DH      3072
#define NCTX    64
#define JLEN    127
#define DC      1024
#define HEADS   8
#define DHEAD   64
#define INNER   512   // HEADS*DHEAD
#define MKV     8128  // NCTX*JLEN
#define MKVPAD  8192

typedef __bf16 bf16x8 __attribute__((ext_vector_type(8)));
typedef float  f32x4  __attribute__((ext_vector_type(4)));

// workspace float offsets
#define OFF_EDOT   0LL
#define OFF_QBF    (OFF_EDOT + N_SEQ)
#define OFF_KBF    (OFF_QBF  + (long long)N_SEQ*INNER/2)     // bf16 896x512
#define OFF_VPM    (OFF_KBF  + (long long)NCTX*128*INNER/2)  // fp32 8128x8
#define OFF_VPNULL (OFF_VPM  + (long long)MKV*8)
#define OFF_WOP    (OFF_VPNULL + 8)
#define OFF_BOP    (OFF_WOP  + INNER)
#define OFF_SBUF   (OFF_BOP  + 16)                           // fp32 64*8*896
#define OFF_ANQ    (OFF_SBUF + (long long)NCTX*HEADS*N_SEQ)  // bf16 896x3072
#define OFF_ANKV   (OFF_ANQ  + (long long)N_SEQ*DH/2)        // bf16 8192x1024
#define OFF_WQT    (OFF_ANKV + (long long)MKVPAD*DC/2)       // bf16 512x3072
#define OFF_WKT    (OFF_WQT  + (long long)INNER*DH/2)        // bf16 512x1024
#define OFF_WVPT   (OFF_WKT  + (long long)INNER*DC/2)        // bf16 16x1024
#define OFF_QSL    (OFF_WVPT + 16*1024/2)                    // fp32 8 x 896x512
#define OFF_KSL    (OFF_QSL  + 8LL*N_SEQ*INNER)              // fp32 2 x 8192x512
#define OFF_VPSL   (OFF_KSL  + 2LL*MKVPAD*INNER)             // fp32 2 x 8192x8
#define OFF_CNT    (OFF_VPSL + 2LL*MKVPAD*8)                 // int 28 + 256

#define NQCNT 28
#define NKCNT 256

// ---------------------------------------------------------------------------
// async global->LDS 16B helper
// ---------------------------------------------------------------------------
__device__ __forceinline__ void async_copy16(const __bf16* g, __bf16* l) {
    __builtin_amdgcn_global_load_lds(
        (const __attribute__((address_space(1))) unsigned int*)g,
        (__attribute__((address_space(3))) unsigned int*)l,
        16, 0, 0);
}

// ---------------------------------------------------------------------------
// LN row helper: stats + normalize + bf16 convert (+ optional Wp dot)
// ---------------------------------------------------------------------------
template <int P>
__device__ __forceinline__
void ln_row(const float* __restrict__ x,
            const float* __restrict__ gamma, const float* __restrict__ beta,
            const float* __restrict__ wp,
            __bf16* __restrict__ o, float* __restrict__ dotout) {
    const int K = P * 1024;
    float4 xv[P];
    float s = 0.f, ss = 0.f, dp = 0.f;
    #pragma unroll
    for (int p = 0; p < P; ++p) {
        xv[p] = *(const float4*)&x[p * 1024 + threadIdx.x * 4];
        s  += xv[p].x + xv[p].y + xv[p].z + xv[p].w;
        ss += xv[p].x * xv[p].x + xv[p].y * xv[p].y
            + xv[p].z * xv[p].z + xv[p].w * xv[p].w;
        if (wp) {
            float4 w4 = *(const float4*)&wp[p * 1024 + threadIdx.x * 4];
            dp += xv[p].x * w4.x + xv[p].y * w4.y + xv[p].z * w4.z + xv[p].w * w4.w;
        }
    }
    #pragma unroll
    for (int ofs = 32; ofs > 0; ofs >>= 1) {
        s  += __shfl_down(s,  ofs);
        ss += __shfl_down(ss, ofs);
        dp += __shfl_down(dp, ofs);
    }
    __shared__ float red[3][4];
    __shared__ float sh_mu, sh_rstd;
    int lane = threadIdx.x & 63, w = threadIdx.x >> 6;
    if (lane == 0) { red[0][w] = s; red[1][w] = ss; red[2][w] = dp; }
    __syncthreads();
    if (threadIdx.x == 0) {
        float S  = red[0][0] + red[0][1] + red[0][2] + red[0][3];
        float SS = red[1][0] + red[1][1] + red[1][2] + red[1][3];
        float m = S / K;
        sh_mu = m;
        sh_rstd = rsqrtf(SS / K - m * m + 1e-5f);
        if (dotout) *dotout = red[2][0] + red[2][1] + red[2][2] + red[2][3];
    }
    __syncthreads();
    float m = sh_mu, r = sh_rstd;
    #pragma unroll
    for (int p = 0; p < P; ++p) {
        int col = p * 1024 + threadIdx.x * 4;
        float4 g4 = *(const float4*)&gamma[col];
        float4 b4 = *(const float4*)&beta[col];
        __bf16 ov[4];
        ov[0] = (__bf16)((xv[p].x - m) * r * g4.x + b4.x);
        ov[1] = (__bf16)((xv[p].y - m) * r * g4.y + b4.y);
        ov[2] = (__bf16)((xv[p].z - m) * r * g4.z + b4.z);
        ov[3] = (__bf16)((xv[p].w - m) * r * g4.w + b4.w);
        *(ushort4*)&o[col] = *(ushort4*)ov;
    }
}

__device__ __forceinline__
void transpose_tile(const float* __restrict__ src, int srcStride,
                    __bf16* __restrict__ dst, int dstStride,
                    int rb, int cb, float t[32][33]) {
    int tx = threadIdx.x & 31, ty = threadIdx.x >> 5;
    #pragma unroll
    for (int i = 0; i < 32; i += 8)
        t[ty + i][tx] = src[(long long)(rb + ty + i) * srcStride + cb + tx];
    __syncthreads();
    #pragma unroll
    for (int i = 0; i < 32; i += 8)
        dst[(long long)(cb + ty + i) * dstStride + rb + tx] = (__bf16)t[tx][ty + i];
}

// ---------------------------------------------------------------------------
// K1: ln_q(896) + ln_kv(8128) + wop(513) + WQT transpose(1536) +
//     WKT transpose(512) + misc zero/null (1)
// ---------------------------------------------------------------------------
#define B_LNQ   N_SEQ
#define B_LNKV  (B_LNQ + MKV)
#define B_WOPE  (B_LNKV + INNER + 1)
#define B_TQ    (B_WOPE + 1536)
#define B_TK    (B_TQ + 512)
#define B_ALL   (B_TK + 1)

__global__ __launch_bounds__(256)
void k1_kernel(const float* __restrict__ emb, const float* __restrict__ ctx,
               const float* __restrict__ qg, const float* __restrict__ qb,
               const float* __restrict__ kvg, const float* __restrict__ kvb,
               const float* __restrict__ Wp, const float* __restrict__ Wo,
               const float* __restrict__ bo, const float* __restrict__ Wq,
               const float* __restrict__ Wkv, const float* __restrict__ null_k,
               __bf16* __restrict__ anq, __bf16* __restrict__ ankv,
               float* __restrict__ edot, float* __restrict__ wop,
               float* __restrict__ bop, __bf16* __restrict__ wqt,
               __bf16* __restrict__ wkt, __bf16* __restrict__ wvpt,
               __bf16* __restrict__ k_bf, int* __restrict__ cnt) {
    __shared__ float t[32][33];
    int b = blockIdx.x;
    if (b < B_LNQ) {
        ln_row<3>(emb + (long long)b * DH, qg, qb, Wp,
                  anq + (long long)b * DH, edot + b);
    } else if (b < B_LNKV) {
        int r = b - B_LNQ;
        ln_row<1>(ctx + (long long)r * DC, kvg, kvb, nullptr,
                  ankv + (long long)r * DC, nullptr);
    } else if (b < B_WOPE) {
        int r = b - B_LNKV;   // 0..512
        const float* src = (r < INNER) ? (Wo + (long long)r * DH) : bo;
        float s = 0.f;
        for (int k = threadIdx.x; k < DH; k += 256) s += src[k] * Wp[k];
        #pragma unroll
        for (int o = 32; o > 0; o >>= 1) s += __shfl_down(s, o);
        __shared__ float red2[4];
        int lane = threadIdx.x & 63, w = threadIdx.x >> 6;
        if (lane == 0) red2[w] = s;
        __syncthreads();
        if (threadIdx.x == 0) {
            float S = red2[0] + red2[1] + red2[2] + red2[3];
            if (r < INNER) wop[r] = S; else *bop = S;
        }
    } else if (b < B_TQ) {
        int bi = b - B_WOPE;
        transpose_tile(Wq, INNER, wqt, DH, (bi >> 4) * 32, (bi & 15) * 32, t);
    } else if (b < B_TK) {
        int bi = b - B_TQ;
        transpose_tile(Wkv, 2 * INNER, wkt, DC, (bi >> 4) * 32, (bi & 15) * 32, t);
    } else {
        // misc: zero wvpt rows 8..15, KBF null-k rows, counters
        for (int i = threadIdx.x; i < 8 * 1024; i += 256)
            wvpt[8 * 1024 + i] = (__bf16)0.f;
        for (int i = threadIdx.x; i < NCTX * INNER; i += 256) {
            int c = i >> 9, d = i & 511;
            k_bf[(long long)(c * 128) * INNER + d] = (__bf16)null_k[d];
        }
        if (threadIdx.x < NQCNT + NKCNT) cnt[threadIdx.x] = 0;
    }
}

// ---------------------------------------------------------------------------
// K1b: wvpt[h][k] (32 blocks, needs wop) + vpnull (1 block)
// ---------------------------------------------------------------------------
__global__ __launch_bounds__(256)
void k1b_kernel(const float* __restrict__ Wkv, const float* __restrict__ wop,
                const float* __restrict__ null_v,
                __bf16* __restrict__ wvpt, float* __restrict__ vpnull) {
    int b = blockIdx.x;
    if (b < 32) {
        int tt = b * 256 + threadIdx.x;   // 0..8191
        int k = tt >> 3, h = tt & 7;
        const float* src = Wkv + (long long)k * (2 * INNER) + INNER + h * 64;
        const float* wv  = wop + h * 64;
        float s = 0.f;
        #pragma unroll 16
        for (int d = 0; d < 64; ++d) s += src[d] * wv[d];
        wvpt[h * 1024 + k] = (__bf16)s;
    } else if (threadIdx.x < 8) {
        int h = threadIdx.x;
        float s = 0.f;
        #pragma unroll 16
        for (int d = 0; d < 64; ++d) s += null_v[h * 64 + d] * wop[h * 64 + d];
        vpnull[h] = s;
    }
}

// ---------------------------------------------------------------------------
// K2: merged projection GEMM, split-K with atomic fixup.
// blocks [0,224):   q, split-K=8, 28 tiles (7m x 4n), K-slice 384
// blocks [224,736): kv, split-K=2, 256 tiles (64m x 4n), K-slice 512
// Last slice-block per tile reduces slices -> QBF bf16 / KBF scatter + VPM.
// ---------------------------------------------------------------------------
__global__ __launch_bounds__(256)
void proj_kernel(const __bf16* __restrict__ ANQ, const __bf16* __restrict__ WQT,
                 const __bf16* __restrict__ ANKV, const __bf16* __restrict__ WKT,
                 const __bf16* __restrict__ WVPT,
                 float* qsl, float* ksl, float* vpsl,
                 __bf16* qbf, __bf16* kbf, float* vpm, int* cnt) {
    __shared__ __align__(16) __bf16 As[128 * 32];
    __shared__ __align__(16) __bf16 Bs[128 * 32];
    __shared__ int sh_last;
    int b = blockIdx.x;
    int tid = threadIdx.x;
    int lane = tid & 63, w = tid >> 6;
    int n16 = lane & 15, quad = lane >> 4;
    int wr = (w >> 1) * 64, wc = (w & 1) * 64;

    const __bf16 *A, *B;
    int K, kbeg, kend, mode, slice, tile;
    long long m0, n0;
    if (b < 224) {
        mode = 0; slice = b / 28; tile = b % 28;
        m0 = (long long)(tile % 7) * 128;
        n0 = (long long)(tile / 7) * 128;
        K = DH; kbeg = slice * 384; kend = kbeg + 384;
        A = ANQ; B = WQT;
    } else {
        mode = 1;
        int b2 = b - 224;
        slice = b2 >> 8; tile = b2 & 255;
        m0 = (long long)(tile & 63) * 128;
        n0 = (long long)(tile >> 6) * 128;
        K = DC; kbeg = slice * 512; kend = kbeg + 512;
        A = ANKV; B = WKT;
    }
    bool dovp = (mode == 1) && (n0 == 0);

    const __bf16* aG = A + (m0 + (tid >> 2)) * K + (tid & 3) * 8;
    const __bf16* bG = B + (n0 + (tid >> 2)) * K + (tid & 3) * 8;
    __bf16* aL = As + tid * 8;
    __bf16* bL = Bs + tid * 8;

    f32x4 acc[4][4], accv[4];
    const f32x4 z = {0.f, 0.f, 0.f, 0.f};
    #pragma unroll
    for (int i = 0; i < 4; ++i) {
        accv[i] = z;
        #pragma unroll
        for (int j = 0; j < 4; ++j) acc[i][j] = z;
    }

    for (int k0 = kbeg; k0 < kend; k0 += 32) {
        async_copy16(aG + k0, aL);
        async_copy16(aG + (long long)64 * K + k0, aL + 2048);
        async_copy16(bG + k0, bL);
        async_copy16(bG + (long long)64 * K + k0, bL + 2048);
        bf16x8 bv;
        if (dovp) bv = *(const bf16x8*)&WVPT[n16 * 1024 + k0 + quad * 8];
        __syncthreads();
        bf16x8 af[4], bfr[4];
        #pragma unroll
        for (int i = 0; i < 4; ++i)
            af[i]  = *(const bf16x8*)&As[(wr + i * 16 + n16) * 32 + quad * 8];
        #pragma unroll
        for (int j = 0; j < 4; ++j)
            bfr[j] = *(const bf16x8*)&Bs[(wc + j * 16 + n16) * 32 + quad * 8];
        #pragma unroll
        for (int i = 0; i < 4; ++i)
            #pragma unroll
            for (int j = 0; j < 4; ++j)
                acc[i][j] = __builtin_amdgcn_mfma_f32_16x16x32_bf16(af[i], bfr[j], acc[i][j], 0, 0, 0);
        if (dovp) {
            #pragma unroll
            for (int i = 0; i < 4; ++i)
                accv[i] = __builtin_amdgcn_mfma_f32_16x16x32_bf16(af[i], bv, accv[i], 0, 0, 0);
        }
        __syncthreads();
    }

    // ---- store slice (fp32) ----
    if (mode == 0) {
        float* dst = qsl + (long long)slice * (N_SEQ * INNER);
        #pragma unroll
        for (int i = 0; i < 4; ++i)
            #pragma unroll
            for (int r = 0; r < 4; ++r) {
                long long gr = m0 + wr + i * 16 + quad * 4 + r;
                #pragma unroll
                for (int j = 0; j < 4; ++j)
                    dst[gr * INNER + n0 + wc + j * 16 + n16] = acc[i][j][r];
            }
    } else {
        float* dst = ksl + (long long)slice * ((long long)MKVPAD * INNER);
        #pragma unroll
        for (int i = 0; i < 4; ++i)
            #pragma unroll
            for (int r = 0; r < 4; ++r) {
                long long gr = m0 + wr + i * 16 + quad * 4 + r;
                #pragma unroll
                for (int j = 0; j < 4; ++j)
                    dst[gr * INNER + n0 + wc + j * 16 + n16] = acc[i][j][r];
                if (dovp && n16 < 8)
                    vpsl[(long long)slice * (MKVPAD * 8) + gr * 8 + n16] = accv[i][r];
            }
    }

    // ---- split-K fixup semaphore ----
    __threadfence();
    __syncthreads();
    if (tid == 0) {
        int old = atomicAdd(&cnt[(mode == 0) ? tile : (NQCNT + tile)], 1);
        sh_last = (old == ((mode == 0) ? 7 : 1));
    }
    __syncthreads();
    if (!sh_last) return;
    __threadfence();

    if (mode == 0) {
        // reduce 8 slices -> QBF bf16. 4096 float4 chunks.
        #pragma unroll
        for (int k = 0; k < 16; ++k) {
            int cid = tid + k * 256;
            int row = cid >> 5, c4 = (cid & 31) * 4;
            long long row_g = m0 + row, col_g = n0 + c4;
            float4 s = {0.f, 0.f, 0.f, 0.f};
            #pragma unroll
            for (int sl = 0; sl < 8; ++sl) {
                float4 v = *(const float4*)&qsl[(long long)sl * (N_SEQ * INNER) + row_g * INNER + col_g];
                s.x += v.x; s.y += v.y; s.z += v.z; s.w += v.w;
            }
            __bf16 ov[4] = {(__bf16)s.x, (__bf16)s.y, (__bf16)s.z, (__bf16)s.w};
            *(ushort4*)&qbf[row_g * INNER + col_g] = *(ushort4*)ov;
        }
    } else {
        const float* s0 = ksl;
        const float* s1 = ksl + (long long)MKVPAD * INNER;
        #pragma unroll
        for (int k = 0; k < 16; ++k) {
            int cid = tid + k * 256;
            int row = cid >> 5, c4 = (cid & 31) * 4;
            long long row_g = m0 + row;
            if (row_g >= MKV) continue;
            long long col_g = n0 + c4;
            int cc = (int)(row_g / JLEN), jj = (int)(row_g % JLEN);
            float4 a = *(const float4*)&s0[row_g * INNER + col_g];
            float4 bb = *(const float4*)&s1[row_g * INNER + col_g];
            __bf16 ov[4] = {(__bf16)(a.x + bb.x), (__bf16)(a.y + bb.y),
                            (__bf16)(a.z + bb.z), (__bf16)(a.w + bb.w)};
            *(ushort4*)&kbf[((long long)(cc * 128) + jj + 1) * INNER + col_g] = *(ushort4*)ov;
        }
        if (n0 == 0) {
            for (int idx = tid; idx < 1024; idx += 256) {
                int row = idx >> 3, hh = idx & 7;
                long long row_g = m0 + row;
                if (row_g >= MKV) continue;
                vpm[row_g * 8 + hh] = vpsl[row_g * 8 + hh]
                                    + vpsl[(long long)MKVPAD * 8 + row_g * 8 + hh];
            }
        }
    }
}

// ---------------------------------------------------------------------------
// K3: attention via MFMA. grid (7, NCTX*HEADS). K-head tile staged into LDS.
// ---------------------------------------------------------------------------
#define KROW 72   // LDS row stride in bf16 (64 data + 8 pad)

__global__ __launch_bounds__(256)
void attn_mfma_kernel(const __bf16* __restrict__ qb, const __bf16* __restrict__ kb,
                      const float* __restrict__ vpm, const float* __restrict__ vpnull,
                      const int* __restrict__ mask, float* __restrict__ s_buf) {
    __shared__ __align__(16) __bf16 ksh[128 * KROW];
    __shared__ float vpsh[128];
    __shared__ float amsh[128];
    int ch = blockIdx.y;
    int h = ch & 7, c = ch >> 3;
    int tid = threadIdx.x;
    int lane = tid & 63, w = tid >> 6;
    int n16 = lane & 15, quad = lane >> 4;

    const __bf16* kbase = kb + (long long)(c * 128) * INNER + h * DHEAD;
    #pragma unroll
    for (int p = 0; p < 4; ++p) {
        int chunk = tid + p * 256;
        int row = chunk >> 3, o = chunk & 7;
        bf16x8 v = *(const bf16x8*)(kbase + (long long)row * INNER + o * 8);
        *(bf16x8*)&ksh[row * KROW + o * 8] = v;
    }
    if (tid < 128) {
        vpsh[tid] = (tid == 0) ? vpnull[h] : vpm[(long long)(c * JLEN + tid - 1) * 8 + h];
        amsh[tid] = (tid == 0) ? 0.f : (mask[tid - 1] ? 0.f : -3.0e38f);
    }
    __syncthreads();

    bf16x8 bF[8][2];
    #pragma unroll
    for (int t = 0; t < 8; ++t)
        #pragma unroll
        for (int s = 0; s < 2; ++s)
            bF[t][s] = *(const bf16x8*)&ksh[(t * 16 + n16) * KROW + s * 32 + quad * 8];

    float vpv[8], am[8];
    #pragma unroll
    for (int t = 0; t < 8; ++t) {
        vpv[t] = vpsh[t * 16 + n16];
        am[t]  = amsh[t * 16 + n16];
    }

    const __bf16* qbase = qb + h * DHEAD;
    bf16x8 aF[2][2];
    int r0s[2];
    #pragma unroll
    for (int it2 = 0; it2 < 2; ++it2) {
        int tile = blockIdx.x * 8 + it2 * 4 + w;
        r0s[it2] = tile * 16;
        const __bf16* qrow = qbase + (long long)(r0s[it2] + n16) * INNER + quad * 8;
        aF[it2][0] = *(const bf16x8*)(qrow);
        aF[it2][1] = *(const bf16x8*)(qrow + 32);
    }

    const f32x4 zero = {0.f, 0.f, 0.f, 0.f};
    #pragma unroll
    for (int it2 = 0; it2 < 2; ++it2) {
        int r0 = r0s[it2];
        f32x4 acc[8];
        #pragma unroll
        for (int t = 0; t < 8; ++t) {
            acc[t] = __builtin_amdgcn_mfma_f32_16x16x32_bf16(aF[it2][0], bF[t][0], zero,   0, 0, 0);
            acc[t] = __builtin_amdgcn_mfma_f32_16x16x32_bf16(aF[it2][1], bF[t][1], acc[t], 0, 0, 0);
        }
        float mloc = -3.0e38f;
        #pragma unroll
        for (int t = 0; t < 8; ++t)
            #pragma unroll
            for (int r = 0; r < 4; ++r)
                mloc = fmaxf(mloc, acc[t][r] * 0.125f + am[t]);
        #pragma unroll
        for (int o = 1; o < 16; o <<= 1) mloc = fmaxf(mloc, __shfl_xor(mloc, o, 16));
        float lr[4] = {0.f, 0.f, 0.f, 0.f}, pr[4] = {0.f, 0.f, 0.f, 0.f};
        #pragma unroll
        for (int t = 0; t < 8; ++t) {
            #pragma unroll
            for (int r = 0; r < 4; ++r) {
                float e = __expf(acc[t][r] * 0.125f + am[t] - mloc);
                lr[r] += e; pr[r] += e * vpv[t];
            }
        }
        #pragma unroll
        for (int o = 1; o < 16; o <<= 1) {
            #pragma unroll
            for (int r = 0; r < 4; ++r) {
                lr[r] += __shfl_xor(lr[r], o, 16);
                pr[r] += __shfl_xor(pr[r], o, 16);
            }
        }
        if (n16 == 0) {
            #pragma unroll
            for (int r = 0; r < 4; ++r)
                s_buf[(long long)ch * N_SEQ + r0 + quad * 4 + r] = pr[r] / lr[r];
        }
    }
}

// ---------------------------------------------------------------------------
// K4: final: pred[n,c] = softplus(e_dot[n] + sum_h s[c,h,n] + bop + bp)
// ---------------------------------------------------------------------------
__global__ void final_kernel(const float* __restrict__ s_buf,
                             const float* __restrict__ e_dot,
                             const float* __restrict__ bop,
                             const float* __restrict__ bp,
                             float* __restrict__ out) {
    int t = blockIdx.x * blockDim.x + threadIdx.x;
    if (t >= N_SEQ * NCTX) return;
    int n = t >> 6, c = t & 63;
    float s = 0.f;
    #pragma unroll
    for (int h = 0; h < HEADS; ++h) s += s_buf[((long long)(c * HEADS + h)) * N_SEQ + n];
    float x = e_dot[n] + s + *bop + *bp;
    out[t] = fmaxf(x, 0.f) + log1pf(__expf(-fabsf(x)));
}

// ---------------------------------------------------------------------------
extern "C" void kernel_launch(void* const* d_in, const int* in_sizes, int n_in,
                              void* d_out, int out_size, void* d_ws, size_t ws_size,
                              hipStream_t stream) {
    const float* emb   = (const float*)d_in[0];
    const float* ctx   = (const float*)d_in[1];
    const int*   cmask = (const int*)  d_in[2];
    const float* qg    = (const float*)d_in[3];
    const float* qb_   = (const float*)d_in[4];
    const float* kvg   = (const float*)d_in[5];
    const float* kvb   = (const float*)d_in[6];
    const float* Wq    = (const float*)d_in[7];
    const float* Wkv   = (const float*)d_in[8];
    const float* nullk = (const float*)d_in[9];
    const float* nullv = (const float*)d_in[10];
    const float* Wo    = (const float*)d_in[11];
    const float* bo    = (const float*)d_in[12];
    const float* Wp    = (const float*)d_in[13];
    const float* bp    = (const float*)d_in[14];
    float* out  = (float*)d_out;
    float* ws_f = (float*)d_ws;

    float*  EDOT   = ws_f + OFF_EDOT;
    __bf16* QBF    = (__bf16*)(ws_f + OFF_QBF);
    __bf16* KBF    = (__bf16*)(ws_f + OFF_KBF);
    float*  VPM    = ws_f + OFF_VPM;
    float*  VPNULL = ws_f + OFF_VPNULL;
    float*  WOP    = ws_f + OFF_WOP;
    float*  BOP    = ws_f + OFF_BOP;
    float*  SBUF   = ws_f + OFF_SBUF;
    __bf16* ANQ    = (__bf16*)(ws_f + OFF_ANQ);
    __bf16* ANKV   = (__bf16*)(ws_f + OFF_ANKV);
    __bf16* WQT    = (__bf16*)(ws_f + OFF_WQT);
    __bf16* WKT    = (__bf16*)(ws_f + OFF_WKT);
    __bf16* WVPT   = (__bf16*)(ws_f + OFF_WVPT);
    float*  QSL    = ws_f + OFF_QSL;
    float*  KSL    = ws_f + OFF_KSL;
    float*  VPSL   = ws_f + OFF_VPSL;
    int*    CNT    = (int*)(ws_f + OFF_CNT);

    k1_kernel<<<B_ALL, 256, 0, stream>>>(
        emb, ctx, qg, qb_, kvg, kvb, Wp, Wo, bo, Wq, Wkv, nullk,
        ANQ, ANKV, EDOT, WOP, BOP, WQT, WKT, WVPT, KBF, CNT);
    k1b_kernel<<<33, 256, 0, stream>>>(Wkv, WOP, nullv, WVPT, VPNULL);
    proj_kernel<<<736, 256, 0, stream>>>(
        ANQ, WQT, ANKV, WKT, WVPT, QSL, KSL, VPSL, QBF, KBF, VPM, CNT);
    attn_mfma_kernel<<<dim3(7, NCTX * HEADS), 256, 0, stream>>>(
        QBF, KBF, VPM, VPNULL, cmask, SBUF);
    final_kernel<<<(N_SEQ * NCTX + 255) / 256, 256, 0, stream>>>(SBUF, EDOT, BOP, bp, out);
}

// Round 8
// 251.986 us; speedup vs baseline: 1.5265x; 1.5265x over previous
//
#include <hip/hip_runtime.h>
#include <math.h>

// ---------------------------------------------------------------------------
// Problem constants
// ---------------------------------------------------------------------------
#define N_SEQ   896
#define DH      3072
#define NCTX    64
#define JLEN    127
#define DC      1024
#define HEADS   8
#define DHEAD   64
#define INNER   512   // HEADS*DHEAD
#define MKV     8128  // NCTX*JLEN
#define MKVPAD  8192

typedef __bf16 bf16x8 __attribute__((ext_vector_type(8)));
typedef float  f32x4  __attribute__((ext_vector_type(4)));

// workspace float offsets
#define OFF_EDOT   0LL
#define OFF_QBF    (OFF_EDOT + N_SEQ)
#define OFF_KBF    (OFF_QBF  + (long long)N_SEQ*INNER/2)     // bf16 896x512
#define OFF_VPM    (OFF_KBF  + (long long)NCTX*128*INNER/2)  // fp32 8128x8
#define OFF_VPNULL (OFF_VPM  + (long long)MKV*8)
#define OFF_BOP    (OFF_VPNULL + 8)
#define OFF_SBUF   (OFF_BOP  + 16)                           // fp32 64*8*896
#define OFF_ANQ    (OFF_SBUF + (long long)NCTX*HEADS*N_SEQ)  // bf16 896x3072
#define OFF_ANKV   (OFF_ANQ  + (long long)N_SEQ*DH/2)        // bf16 8192x1024
#define OFF_WQT    (OFF_ANKV + (long long)MKVPAD*DC/2)       // bf16 512x3072
#define OFF_WKT    (OFF_WQT  + (long long)INNER*DH/2)        // bf16 512x1024
#define OFF_WVPT   (OFF_WKT  + (long long)INNER*DC/2)        // bf16 16x1024
#define OFF_QSL    (OFF_WVPT + 16*1024/2)                    // fp32 8 x 896x512

// ---------------------------------------------------------------------------
// async global->LDS 16B helper
// ---------------------------------------------------------------------------
__device__ __forceinline__ void async_copy16(const __bf16* g, __bf16* l) {
    __builtin_amdgcn_global_load_lds(
        (const __attribute__((address_space(1))) unsigned int*)g,
        (__attribute__((address_space(3))) unsigned int*)l,
        16, 0, 0);
}

// ---------------------------------------------------------------------------
// LN row helper: stats + normalize + bf16 convert (+ optional Wp dot)
// ---------------------------------------------------------------------------
template <int P>
__device__ __forceinline__
void ln_row(const float* __restrict__ x,
            const float* __restrict__ gamma, const float* __restrict__ beta,
            const float* __restrict__ wp,
            __bf16* __restrict__ o, float* __restrict__ dotout) {
    const int K = P * 1024;
    float4 xv[P];
    float s = 0.f, ss = 0.f, dp = 0.f;
    #pragma unroll
    for (int p = 0; p < P; ++p) {
        xv[p] = *(const float4*)&x[p * 1024 + threadIdx.x * 4];
        s  += xv[p].x + xv[p].y + xv[p].z + xv[p].w;
        ss += xv[p].x * xv[p].x + xv[p].y * xv[p].y
            + xv[p].z * xv[p].z + xv[p].w * xv[p].w;
        if (wp) {
            float4 w4 = *(const float4*)&wp[p * 1024 + threadIdx.x * 4];
            dp += xv[p].x * w4.x + xv[p].y * w4.y + xv[p].z * w4.z + xv[p].w * w4.w;
        }
    }
    #pragma unroll
    for (int ofs = 32; ofs > 0; ofs >>= 1) {
        s  += __shfl_down(s,  ofs);
        ss += __shfl_down(ss, ofs);
        dp += __shfl_down(dp, ofs);
    }
    __shared__ float red[3][4];
    __shared__ float sh_mu, sh_rstd;
    int lane = threadIdx.x & 63, w = threadIdx.x >> 6;
    if (lane == 0) { red[0][w] = s; red[1][w] = ss; red[2][w] = dp; }
    __syncthreads();
    if (threadIdx.x == 0) {
        float S  = red[0][0] + red[0][1] + red[0][2] + red[0][3];
        float SS = red[1][0] + red[1][1] + red[1][2] + red[1][3];
        float m = S / K;
        sh_mu = m;
        sh_rstd = rsqrtf(SS / K - m * m + 1e-5f);
        if (dotout) *dotout = red[2][0] + red[2][1] + red[2][2] + red[2][3];
    }
    __syncthreads();
    float m = sh_mu, r = sh_rstd;
    #pragma unroll
    for (int p = 0; p < P; ++p) {
        int col = p * 1024 + threadIdx.x * 4;
        float4 g4 = *(const float4*)&gamma[col];
        float4 b4 = *(const float4*)&beta[col];
        __bf16 ov[4];
        ov[0] = (__bf16)((xv[p].x - m) * r * g4.x + b4.x);
        ov[1] = (__bf16)((xv[p].y - m) * r * g4.y + b4.y);
        ov[2] = (__bf16)((xv[p].z - m) * r * g4.z + b4.z);
        ov[3] = (__bf16)((xv[p].w - m) * r * g4.w + b4.w);
        *(ushort4*)&o[col] = *(ushort4*)ov;
    }
}

__device__ __forceinline__
void transpose_tile(const float* __restrict__ src, int srcStride,
                    __bf16* __restrict__ dst, int dstStride,
                    int rb, int cb, float t[32][33]) {
    int tx = threadIdx.x & 31, ty = threadIdx.x >> 5;
    #pragma unroll
    for (int i = 0; i < 32; i += 8)
        t[ty + i][tx] = src[(long long)(rb + ty + i) * srcStride + cb + tx];
    __syncthreads();
    #pragma unroll
    for (int i = 0; i < 32; i += 8)
        dst[(long long)(cb + ty + i) * dstStride + rb + tx] = (__bf16)t[tx][ty + i];
}

// ---------------------------------------------------------------------------
// K1: ln_q(896) + ln_kv(8128) + WQT transpose(1536) + WKT transpose(512) +
//     self-contained wvp per head(8) + bop(1) + misc(1)
// ---------------------------------------------------------------------------
#define B_LNQ   N_SEQ
#define B_LNKV  (B_LNQ + MKV)
#define B_TQ    (B_LNKV + 1536)
#define B_TK    (B_TQ + 512)
#define B_WVP   (B_TK + 8)
#define B_BOP   (B_WVP + 1)
#define B_ALL   (B_BOP + 1)

__global__ __launch_bounds__(256)
void k1_kernel(const float* __restrict__ emb, const float* __restrict__ ctx,
               const float* __restrict__ qg, const float* __restrict__ qb,
               const float* __restrict__ kvg, const float* __restrict__ kvb,
               const float* __restrict__ Wp, const float* __restrict__ Wo,
               const float* __restrict__ bo, const float* __restrict__ Wq,
               const float* __restrict__ Wkv, const float* __restrict__ null_k,
               const float* __restrict__ null_v,
               __bf16* __restrict__ anq, __bf16* __restrict__ ankv,
               float* __restrict__ edot, float* __restrict__ bop,
               __bf16* __restrict__ wqt, __bf16* __restrict__ wkt,
               __bf16* __restrict__ wvpt, float* __restrict__ vpnull,
               __bf16* __restrict__ k_bf) {
    __shared__ float t[32][33];
    int b = blockIdx.x;
    int tid = threadIdx.x;
    if (b < B_LNQ) {
        ln_row<3>(emb + (long long)b * DH, qg, qb, Wp,
                  anq + (long long)b * DH, edot + b);
    } else if (b < B_LNKV) {
        int r = b - B_LNQ;
        ln_row<1>(ctx + (long long)r * DC, kvg, kvb, nullptr,
                  ankv + (long long)r * DC, nullptr);
    } else if (b < B_TQ) {
        int bi = b - B_LNKV;
        transpose_tile(Wq, INNER, wqt, DH, (bi >> 4) * 32, (bi & 15) * 32, t);
    } else if (b < B_TK) {
        int bi = b - B_TQ;
        transpose_tile(Wkv, 2 * INNER, wkt, DC, (bi >> 4) * 32, (bi & 15) * 32, t);
    } else if (b < B_WVP) {
        // self-contained: compute wop slice for head h, then wvpt row + vpnull
        int h = b - B_TK;
        __shared__ float part[64][4];
        __shared__ float wops[64];
        int v = tid >> 2, p = tid & 3;
        const float* row = Wo + ((long long)(h * 64 + v)) * DH + p * 768;
        const float* wpp = Wp + p * 768;
        float s = 0.f;
        #pragma unroll 8
        for (int e = 0; e < 768; ++e) s += row[e] * wpp[e];
        part[v][p] = s;
        __syncthreads();
        if (tid < 64) wops[tid] = part[tid][0] + part[tid][1] + part[tid][2] + part[tid][3];
        __syncthreads();
        if (tid == 64) {
            float sn = 0.f;
            #pragma unroll 16
            for (int d = 0; d < 64; ++d) sn += null_v[h * 64 + d] * wops[d];
            vpnull[h] = sn;
        }
        #pragma unroll
        for (int kk = 0; kk < 4; ++kk) {
            int k = kk * 256 + tid;
            const float* src = Wkv + (long long)k * (2 * INNER) + INNER + h * 64;
            float sv = 0.f;
            #pragma unroll 16
            for (int d = 0; d < 64; ++d) sv += src[d] * wops[d];
            wvpt[h * 1024 + k] = (__bf16)sv;
        }
    } else if (b < B_BOP) {
        float s = 0.f;
        for (int k = tid; k < DH; k += 256) s += bo[k] * Wp[k];
        #pragma unroll
        for (int o = 32; o > 0; o >>= 1) s += __shfl_down(s, o);
        __shared__ float red2[4];
        int lane = tid & 63, w = tid >> 6;
        if (lane == 0) red2[w] = s;
        __syncthreads();
        if (tid == 0) *bop = red2[0] + red2[1] + red2[2] + red2[3];
    } else {
        // misc: zero wvpt rows 8..15, KBF null-k rows
        for (int i = tid; i < 8 * 1024; i += 256)
            wvpt[8 * 1024 + i] = (__bf16)0.f;
        for (int i = tid; i < NCTX * INNER; i += 256) {
            int c = i >> 9, d = i & 511;
            k_bf[(long long)(c * 128) * INNER + d] = (__bf16)null_k[d];
        }
    }
}

// ---------------------------------------------------------------------------
// K2: merged projection GEMM (bf16 MFMA, BK=32, global_load_lds, no fences)
// blocks [0,224):   q, 128x128 tile, split-K=8 -> fp32 qsl[s][896][512]
// blocks [224,736): kv, 128x64 tile, full K -> bf16 KBF scatter; n0==0 tiles
//                   also compute vp via WVPT B-fragment (cols 0..7)
// ---------------------------------------------------------------------------
__global__ __launch_bounds__(256)
void proj_kernel(const __bf16* __restrict__ ANQ, const __bf16* __restrict__ WQT,
                 const __bf16* __restrict__ ANKV, const __bf16* __restrict__ WKT,
                 const __bf16* __restrict__ WVPT,
                 float* __restrict__ qsl, __bf16* __restrict__ kout,
                 float* __restrict__ vpm) {
    __shared__ __align__(16) __bf16 As[128 * 32];
    __shared__ __align__(16) __bf16 Bs[128 * 32];
    int b = blockIdx.x;
    int tid = threadIdx.x;
    int lane = tid & 63, w = tid >> 6;
    int n16 = lane & 15, quad = lane >> 4;
    const f32x4 z = {0.f, 0.f, 0.f, 0.f};

    if (b < 224) {
        // ---------------- q path: 128x128, split-K=8 ----------------
        int slice = b / 28, tile = b % 28;
        long long m0 = (long long)(tile % 7) * 128;
        long long n0 = (long long)(tile / 7) * 128;
        int kbeg = slice * 384, kend = kbeg + 384;
        int wr = (w >> 1) * 64, wc = (w & 1) * 64;
        const __bf16* aG = ANQ + (m0 + (tid >> 2)) * DH + (tid & 3) * 8;
        const __bf16* bG = WQT + (n0 + (tid >> 2)) * DH + (tid & 3) * 8;
        __bf16* aL = As + tid * 8;
        __bf16* bL = Bs + tid * 8;
        f32x4 acc[4][4];
        #pragma unroll
        for (int i = 0; i < 4; ++i)
            #pragma unroll
            for (int j = 0; j < 4; ++j) acc[i][j] = z;
        for (int k0 = kbeg; k0 < kend; k0 += 32) {
            async_copy16(aG + k0, aL);
            async_copy16(aG + (long long)64 * DH + k0, aL + 2048);
            async_copy16(bG + k0, bL);
            async_copy16(bG + (long long)64 * DH + k0, bL + 2048);
            __syncthreads();
            bf16x8 af[4], bfr[4];
            #pragma unroll
            for (int i = 0; i < 4; ++i)
                af[i]  = *(const bf16x8*)&As[(wr + i * 16 + n16) * 32 + quad * 8];
            #pragma unroll
            for (int j = 0; j < 4; ++j)
                bfr[j] = *(const bf16x8*)&Bs[(wc + j * 16 + n16) * 32 + quad * 8];
            #pragma unroll
            for (int i = 0; i < 4; ++i)
                #pragma unroll
                for (int j = 0; j < 4; ++j)
                    acc[i][j] = __builtin_amdgcn_mfma_f32_16x16x32_bf16(af[i], bfr[j], acc[i][j], 0, 0, 0);
            __syncthreads();
        }
        float* dst = qsl + (long long)slice * (N_SEQ * INNER);
        #pragma unroll
        for (int i = 0; i < 4; ++i)
            #pragma unroll
            for (int r = 0; r < 4; ++r) {
                long long gr = m0 + wr + i * 16 + quad * 4 + r;
                #pragma unroll
                for (int j = 0; j < 4; ++j)
                    dst[gr * INNER + n0 + wc + j * 16 + n16] = acc[i][j][r];
            }
    } else {
        // ---------------- kv path: 128x64 tile, full K=1024 ----------------
        int b2 = b - 224;
        long long m0 = (long long)(b2 >> 3) * 128;
        long long n0 = (long long)(b2 & 7) * 64;
        int wr = (w >> 1) * 64, wc = (w & 1) * 32;
        bool dovp = (n0 == 0) && ((w & 1) == 0);
        const __bf16* aG = ANKV + (m0 + (tid >> 2)) * DC + (tid & 3) * 8;
        const __bf16* bG = WKT  + (n0 + (tid >> 2)) * DC + (tid & 3) * 8;
        __bf16* aL = As + tid * 8;
        __bf16* bL = Bs + tid * 8;
        f32x4 acc[4][2], accv[4];
        #pragma unroll
        for (int i = 0; i < 4; ++i) {
            accv[i] = z;
            acc[i][0] = z; acc[i][1] = z;
        }
        for (int k0 = 0; k0 < DC; k0 += 32) {
            async_copy16(aG + k0, aL);
            async_copy16(aG + (long long)64 * DC + k0, aL + 2048);
            async_copy16(bG + k0, bL);
            bf16x8 bv;
            if (dovp) bv = *(const bf16x8*)&WVPT[n16 * 1024 + k0 + quad * 8];
            __syncthreads();
            bf16x8 af[4], bfr[2];
            #pragma unroll
            for (int i = 0; i < 4; ++i)
                af[i]  = *(const bf16x8*)&As[(wr + i * 16 + n16) * 32 + quad * 8];
            #pragma unroll
            for (int j = 0; j < 2; ++j)
                bfr[j] = *(const bf16x8*)&Bs[(wc + j * 16 + n16) * 32 + quad * 8];
            #pragma unroll
            for (int i = 0; i < 4; ++i) {
                acc[i][0] = __builtin_amdgcn_mfma_f32_16x16x32_bf16(af[i], bfr[0], acc[i][0], 0, 0, 0);
                acc[i][1] = __builtin_amdgcn_mfma_f32_16x16x32_bf16(af[i], bfr[1], acc[i][1], 0, 0, 0);
            }
            if (dovp) {
                #pragma unroll
                for (int i = 0; i < 4; ++i)
                    accv[i] = __builtin_amdgcn_mfma_f32_16x16x32_bf16(af[i], bv, accv[i], 0, 0, 0);
            }
            __syncthreads();
        }
        #pragma unroll
        for (int i = 0; i < 4; ++i)
            #pragma unroll
            for (int r = 0; r < 4; ++r) {
                long long gr = m0 + wr + i * 16 + quad * 4 + r;
                if (gr >= MKV) continue;
                int cc = (int)(gr / JLEN), jj = (int)(gr % JLEN);
                #pragma unroll
                for (int j = 0; j < 2; ++j) {
                    long long gc = n0 + wc + j * 16 + n16;
                    kout[((long long)(cc * 128) + jj + 1) * INNER + gc] = (__bf16)acc[i][j][r];
                }
                if (dovp && n16 < 8) vpm[gr * 8 + n16] = accv[i][r];
            }
    }
}

// ---------------------------------------------------------------------------
// K3: reduce 8 q split-K slices -> bf16 (float4 per thread)
// ---------------------------------------------------------------------------
__global__ void qreduce_kernel(const float* __restrict__ qsl, __bf16* __restrict__ qbf) {
    int t4 = blockIdx.x * 256 + threadIdx.x;   // 114688 float4 chunks
    const int SL = N_SEQ * INNER / 4;
    float4 s = {0.f, 0.f, 0.f, 0.f};
    #pragma unroll
    for (int k = 0; k < 8; ++k) {
        float4 v = ((const float4*)qsl)[(long long)k * SL + t4];
        s.x += v.x; s.y += v.y; s.z += v.z; s.w += v.w;
    }
    __bf16 ov[4] = {(__bf16)s.x, (__bf16)s.y, (__bf16)s.z, (__bf16)s.w};
    ((ushort4*)qbf)[t4] = *(ushort4*)ov;
}

// ---------------------------------------------------------------------------
// K4: attention via MFMA. grid (7, NCTX*HEADS). K-head tile staged into LDS.
// ---------------------------------------------------------------------------
#define KROW 72   // LDS row stride in bf16 (64 data + 8 pad)

__global__ __launch_bounds__(256)
void attn_mfma_kernel(const __bf16* __restrict__ qb, const __bf16* __restrict__ kb,
                      const float* __restrict__ vpm, const float* __restrict__ vpnull,
                      const int* __restrict__ mask, float* __restrict__ s_buf) {
    __shared__ __align__(16) __bf16 ksh[128 * KROW];
    __shared__ float vpsh[128];
    __shared__ float amsh[128];
    int ch = blockIdx.y;
    int h = ch & 7, c = ch >> 3;
    int tid = threadIdx.x;
    int lane = tid & 63, w = tid >> 6;
    int n16 = lane & 15, quad = lane >> 4;

    const __bf16* kbase = kb + (long long)(c * 128) * INNER + h * DHEAD;
    #pragma unroll
    for (int p = 0; p < 4; ++p) {
        int chunk = tid + p * 256;
        int row = chunk >> 3, o = chunk & 7;
        bf16x8 v = *(const bf16x8*)(kbase + (long long)row * INNER + o * 8);
        *(bf16x8*)&ksh[row * KROW + o * 8] = v;
    }
    if (tid < 128) {
        vpsh[tid] = (tid == 0) ? vpnull[h] : vpm[(long long)(c * JLEN + tid - 1) * 8 + h];
        amsh[tid] = (tid == 0) ? 0.f : (mask[tid - 1] ? 0.f : -3.0e38f);
    }
    __syncthreads();

    bf16x8 bF[8][2];
    #pragma unroll
    for (int t = 0; t < 8; ++t)
        #pragma unroll
        for (int s = 0; s < 2; ++s)
            bF[t][s] = *(const bf16x8*)&ksh[(t * 16 + n16) * KROW + s * 32 + quad * 8];

    float vpv[8], am[8];
    #pragma unroll
    for (int t = 0; t < 8; ++t) {
        vpv[t] = vpsh[t * 16 + n16];
        am[t]  = amsh[t * 16 + n16];
    }

    const __bf16* qbase = qb + h * DHEAD;
    bf16x8 aF[2][2];
    int r0s[2];
    #pragma unroll
    for (int it2 = 0; it2 < 2; ++it2) {
        int tile = blockIdx.x * 8 + it2 * 4 + w;
        r0s[it2] = tile * 16;
        const __bf16* qrow = qbase + (long long)(r0s[it2] + n16) * INNER + quad * 8;
        aF[it2][0] = *(const bf16x8*)(qrow);
        aF[it2][1] = *(const bf16x8*)(qrow + 32);
    }

    const f32x4 zero = {0.f, 0.f, 0.f, 0.f};
    #pragma unroll
    for (int it2 = 0; it2 < 2; ++it2) {
        int r0 = r0s[it2];
        f32x4 acc[8];
        #pragma unroll
        for (int t = 0; t < 8; ++t) {
            acc[t] = __builtin_amdgcn_mfma_f32_16x16x32_bf16(aF[it2][0], bF[t][0], zero,   0, 0, 0);
            acc[t] = __builtin_amdgcn_mfma_f32_16x16x32_bf16(aF[it2][1], bF[t][1], acc[t], 0, 0, 0);
        }
        float mloc = -3.0e38f;
        #pragma unroll
        for (int t = 0; t < 8; ++t)
            #pragma unroll
            for (int r = 0; r < 4; ++r)
                mloc = fmaxf(mloc, acc[t][r] * 0.125f + am[t]);
        #pragma unroll
        for (int o = 1; o < 16; o <<= 1) mloc = fmaxf(mloc, __shfl_xor(mloc, o, 16));
        float lr[4] = {0.f, 0.f, 0.f, 0.f}, pr[4] = {0.f, 0.f, 0.f, 0.f};
        #pragma unroll
        for (int t = 0; t < 8; ++t) {
            #pragma unroll
            for (int r = 0; r < 4; ++r) {
                float e = __expf(acc[t][r] * 0.125f + am[t] - mloc);
                lr[r] += e; pr[r] += e * vpv[t];
            }
        }
        #pragma unroll
        for (int o = 1; o < 16; o <<= 1) {
            #pragma unroll
            for (int r = 0; r < 4; ++r) {
                lr[r] += __shfl_xor(lr[r], o, 16);
                pr[r] += __shfl_xor(pr[r], o, 16);
            }
        }
        if (n16 == 0) {
            #pragma unroll
            for (int r = 0; r < 4; ++r)
                s_buf[(long long)ch * N_SEQ + r0 + quad * 4 + r] = pr[r] / lr[r];
        }
    }
}

// ---------------------------------------------------------------------------
// K5: final: pred[n,c] = softplus(e_dot[n] + sum_h s[c,h,n] + bop + bp)
// ---------------------------------------------------------------------------
__global__ void final_kernel(const float* __restrict__ s_buf,
                             const float* __restrict__ e_dot,
                             const float* __restrict__ bop,
                             const float* __restrict__ bp,
                             float* __restrict__ out) {
    int t = blockIdx.x * blockDim.x + threadIdx.x;
    if (t >= N_SEQ * NCTX) return;
    int n = t >> 6, c = t & 63;
    float s = 0.f;
    #pragma unroll
    for (int h = 0; h < HEADS; ++h) s += s_buf[((long long)(c * HEADS + h)) * N_SEQ + n];
    float x = e_dot[n] + s + *bop + *bp;
    out[t] = fmaxf(x, 0.f) + log1pf(__expf(-fabsf(x)));
}

// ---------------------------------------------------------------------------
extern "C" void kernel_launch(void* const* d_in, const int* in_sizes, int n_in,
                              void* d_out, int out_size, void* d_ws, size_t ws_size,
                              hipStream_t stream) {
    const float* emb   = (const float*)d_in[0];
    const float* ctx   = (const float*)d_in[1];
    const int*   cmask = (const int*)  d_in[2];
    const float* qg    = (const float*)d_in[3];
    const float* qb_   = (const float*)d_in[4];
    const float* kvg   = (const float*)d_in[5];
    const float* kvb   = (const float*)d_in[6];
    const float* Wq    = (const float*)d_in[7];
    const float* Wkv   = (const float*)d_in[8];
    const float* nullk = (const float*)d_in[9];
    const float* nullv = (const float*)d_in[10];
    const float* Wo    = (const float*)d_in[11];
    const float* bo    = (const float*)d_in[12];
    const float* Wp    = (const float*)d_in[13];
    const float* bp    = (const float*)d_in[14];
    float* out  = (float*)d_out;
    float* ws_f = (float*)d_ws;

    float*  EDOT   = ws_f + OFF_EDOT;
    __bf16* QBF    = (__bf16*)(ws_f + OFF_QBF);
    __bf16* KBF    = (__bf16*)(ws_f + OFF_KBF);
    float*  VPM    = ws_f + OFF_VPM;
    float*  VPNULL = ws_f + OFF_VPNULL;
    float*  BOP    = ws_f + OFF_BOP;
    float*  SBUF   = ws_f + OFF_SBUF;
    __bf16* ANQ    = (__bf16*)(ws_f + OFF_ANQ);
    __bf16* ANKV   = (__bf16*)(ws_f + OFF_ANKV);
    __bf16* WQT    = (__bf16*)(ws_f + OFF_WQT);
    __bf16* WKT    = (__bf16*)(ws_f + OFF_WKT);
    __bf16* WVPT   = (__bf16*)(ws_f + OFF_WVPT);
    float*  QSL    = ws_f + OFF_QSL;

    k1_kernel<<<B_ALL, 256, 0, stream>>>(
        emb, ctx, qg, qb_, kvg, kvb, Wp, Wo, bo, Wq, Wkv, nullk, nullv,
        ANQ, ANKV, EDOT, BOP, WQT, WKT, WVPT, VPNULL, KBF);
    proj_kernel<<<736, 256, 0, stream>>>(
        ANQ, WQT, ANKV, WKT, WVPT, QSL, KBF, VPM);
    qreduce_kernel<<<(N_SEQ * INNER / 4) / 256, 256, 0, stream>>>(QSL, QBF);
    attn_mfma_kernel<<<dim3(7, NCTX * HEADS), 256, 0, stream>>>(
        QBF, KBF, VPM, VPNULL, cmask, SBUF);
    final_kernel<<<(N_SEQ * NCTX + 255) / 256, 256, 0, stream>>>(SBUF, EDOT, BOP, bp, out);
}

// Round 10
// 220.742 us; speedup vs baseline: 1.7425x; 1.1415x over previous
//
#include <hip/hip_runtime.h>
#include <math.h>

// ---------------------------------------------------------------------------
// Problem constants
// ---------------------------------------------------------------------------
#define N_SEQ   896
#define DH      3072
#define NCTX    64
#define JLEN    127
#define DC      1024
#define HEADS   8
#define DHEAD   64
#define INNER   512   // HEADS*DHEAD
#define MKV     8128  // NCTX*JLEN
#define MKVPAD  8192

typedef __bf16 bf16x8 __attribute__((ext_vector_type(8)));
typedef float  f32x4  __attribute__((ext_vector_type(4)));

// workspace float offsets
#define OFF_EDOT   0LL
#define OFF_QBF    (OFF_EDOT + N_SEQ)
#define OFF_KBF    (OFF_QBF  + (long long)N_SEQ*INNER/2)     // bf16 896x512
#define OFF_VPM    (OFF_KBF  + (long long)NCTX*128*INNER/2)  // fp32 8128x8
#define OFF_VPNULL (OFF_VPM  + (long long)MKV*8)
#define OFF_WOP    (OFF_VPNULL + 8)
#define OFF_BOP    (OFF_WOP  + INNER)
#define OFF_SBUF   (OFF_BOP  + 16)                           // fp32 64*8*896
#define OFF_ANQ    (OFF_SBUF + (long long)NCTX*HEADS*N_SEQ)  // bf16 896x3072
#define OFF_ANKV   (OFF_ANQ  + (long long)N_SEQ*DH/2)        // bf16 8192x1024
#define OFF_WQT    (OFF_ANKV + (long long)MKVPAD*DC/2)       // bf16 512x3072
#define OFF_WKT    (OFF_WQT  + (long long)INNER*DH/2)        // bf16 512x1024
#define OFF_WVPT   (OFF_WKT  + (long long)INNER*DC/2)        // bf16 16x1024
#define OFF_QSL    (OFF_WVPT + 16*1024/2)                    // fp32 8 x 896x512

// ---------------------------------------------------------------------------
// async global->LDS 16B helper
// ---------------------------------------------------------------------------
__device__ __forceinline__ void async_copy16(const __bf16* g, __bf16* l) {
    __builtin_amdgcn_global_load_lds(
        (const __attribute__((address_space(1))) unsigned int*)g,
        (__attribute__((address_space(3))) unsigned int*)l,
        16, 0, 0);
}

// ---------------------------------------------------------------------------
// LN row helper (block-per-row, proven): stats + normalize + bf16 convert
// ---------------------------------------------------------------------------
template <int P>
__device__ __forceinline__
void ln_row(const float* __restrict__ x,
            const float* __restrict__ gamma, const float* __restrict__ beta,
            const float* __restrict__ wp,
            __bf16* __restrict__ o, float* __restrict__ dotout) {
    const int K = P * 1024;
    float4 xv[P];
    float s = 0.f, ss = 0.f, dp = 0.f;
    #pragma unroll
    for (int p = 0; p < P; ++p) {
        xv[p] = *(const float4*)&x[p * 1024 + threadIdx.x * 4];
        s  += xv[p].x + xv[p].y + xv[p].z + xv[p].w;
        ss += xv[p].x * xv[p].x + xv[p].y * xv[p].y
            + xv[p].z * xv[p].z + xv[p].w * xv[p].w;
        if (wp) {
            float4 w4 = *(const float4*)&wp[p * 1024 + threadIdx.x * 4];
            dp += xv[p].x * w4.x + xv[p].y * w4.y + xv[p].z * w4.z + xv[p].w * w4.w;
        }
    }
    #pragma unroll
    for (int ofs = 32; ofs > 0; ofs >>= 1) {
        s  += __shfl_down(s,  ofs);
        ss += __shfl_down(ss, ofs);
        dp += __shfl_down(dp, ofs);
    }
    __shared__ float red[3][4];
    __shared__ float sh_mu, sh_rstd;
    int lane = threadIdx.x & 63, w = threadIdx.x >> 6;
    if (lane == 0) { red[0][w] = s; red[1][w] = ss; red[2][w] = dp; }
    __syncthreads();
    if (threadIdx.x == 0) {
        float S  = red[0][0] + red[0][1] + red[0][2] + red[0][3];
        float SS = red[1][0] + red[1][1] + red[1][2] + red[1][3];
        float m = S / K;
        sh_mu = m;
        sh_rstd = rsqrtf(SS / K - m * m + 1e-5f);
        if (dotout) *dotout = red[2][0] + red[2][1] + red[2][2] + red[2][3];
    }
    __syncthreads();
    float m = sh_mu, r = sh_rstd;
    #pragma unroll
    for (int p = 0; p < P; ++p) {
        int col = p * 1024 + threadIdx.x * 4;
        float4 g4 = *(const float4*)&gamma[col];
        float4 b4 = *(const float4*)&beta[col];
        __bf16 ov[4];
        ov[0] = (__bf16)((xv[p].x - m) * r * g4.x + b4.x);
        ov[1] = (__bf16)((xv[p].y - m) * r * g4.y + b4.y);
        ov[2] = (__bf16)((xv[p].z - m) * r * g4.z + b4.z);
        ov[3] = (__bf16)((xv[p].w - m) * r * g4.w + b4.w);
        *(ushort4*)&o[col] = *(ushort4*)ov;
    }
}

// ---------------------------------------------------------------------------
// K1: fused ln_q (896) + ln_kv (8128) + wop/bop (513) by block range
// ---------------------------------------------------------------------------
__global__ __launch_bounds__(256)
void ln_wop_kernel(const float* __restrict__ emb, const float* __restrict__ ctx,
                   const float* __restrict__ qg, const float* __restrict__ qb,
                   const float* __restrict__ kvg, const float* __restrict__ kvb,
                   const float* __restrict__ Wp, const float* __restrict__ Wo,
                   const float* __restrict__ bo,
                   __bf16* __restrict__ anq, __bf16* __restrict__ ankv,
                   float* __restrict__ edot, float* __restrict__ wop,
                   float* __restrict__ bop) {
    int b = blockIdx.x;
    if (b < N_SEQ) {
        ln_row<3>(emb + (long long)b * DH, qg, qb, Wp,
                  anq + (long long)b * DH, edot + b);
    } else if (b < N_SEQ + MKV) {
        int r = b - N_SEQ;
        ln_row<1>(ctx + (long long)r * DC, kvg, kvb, nullptr,
                  ankv + (long long)r * DC, nullptr);
    } else {
        int r = b - (N_SEQ + MKV);   // 0..512
        const float* src = (r < INNER) ? (Wo + (long long)r * DH) : bo;
        float s = 0.f;
        for (int k = threadIdx.x; k < DH; k += 256) s += src[k] * Wp[k];
        #pragma unroll
        for (int o = 32; o > 0; o >>= 1) s += __shfl_down(s, o);
        __shared__ float red2[4];
        int lane = threadIdx.x & 63, w = threadIdx.x >> 6;
        if (lane == 0) red2[w] = s;
        __syncthreads();
        if (threadIdx.x == 0) {
            float S = red2[0] + red2[1] + red2[2] + red2[3];
            if (r < INNER) wop[r] = S; else *bop = S;
        }
    }
}

// ---------------------------------------------------------------------------
// K2: fused weight prep: WQT transpose (1536) + WKT transpose (512) +
//     wvpt (32) + null_k/vpnull/zero (1)
// ---------------------------------------------------------------------------
__device__ __forceinline__
void transpose_tile(const float* __restrict__ src, int srcStride,
                    __bf16* __restrict__ dst, int dstStride,
                    int rb, int cb, float t[32][33]) {
    int tx = threadIdx.x & 31, ty = threadIdx.x >> 5;
    #pragma unroll
    for (int i = 0; i < 32; i += 8)
        t[ty + i][tx] = src[(long long)(rb + ty + i) * srcStride + cb + tx];
    __syncthreads();
    #pragma unroll
    for (int i = 0; i < 32; i += 8)
        dst[(long long)(cb + ty + i) * dstStride + rb + tx] = (__bf16)t[tx][ty + i];
}

__global__ __launch_bounds__(256)
void prep2_kernel(const float* __restrict__ Wq, const float* __restrict__ Wkv,
                  const float* __restrict__ wop,
                  const float* __restrict__ null_v, const float* __restrict__ null_k,
                  __bf16* __restrict__ wqt, __bf16* __restrict__ wkt,
                  __bf16* __restrict__ wvpt, float* __restrict__ vpnull,
                  __bf16* __restrict__ k_bf) {
    __shared__ float t[32][33];
    int b = blockIdx.x;
    if (b < 1536) {
        int rb = (b >> 4) * 32, cb = (b & 15) * 32;
        transpose_tile(Wq, INNER, wqt, DH, rb, cb, t);
    } else if (b < 2048) {
        int bi = b - 1536;
        int rb = (bi >> 4) * 32, cb = (bi & 15) * 32;
        transpose_tile(Wkv, 2 * INNER, wkt, DC, rb, cb, t);
    } else if (b < 2080) {
        int tt = (b - 2048) * 256 + threadIdx.x;   // 0..8191
        int k = tt >> 3, h = tt & 7;
        const float* src = Wkv + (long long)k * (2 * INNER) + INNER + h * 64;
        const float* wv  = wop + h * 64;
        float s = 0.f;
        #pragma unroll 16
        for (int d = 0; d < 64; ++d) s += src[d] * wv[d];
        wvpt[h * 1024 + k] = (__bf16)s;
    } else {
        for (int i = threadIdx.x; i < 8 * 1024; i += 256)
            wvpt[8 * 1024 + i] = (__bf16)0.f;
        for (int i = threadIdx.x; i < NCTX * INNER; i += 256) {
            int c = i >> 9, d = i & 511;
            k_bf[(long long)(c * 128) * INNER + d] = (__bf16)null_k[d];
        }
        if (threadIdx.x < 8) {
            int h = threadIdx.x;
            float s = 0.f;
            #pragma unroll 16
            for (int d = 0; d < 64; ++d) s += null_v[h * 64 + d] * wop[h * 64 + d];
            vpnull[h] = s;
        }
    }
}

// ---------------------------------------------------------------------------
// K3: merged projection GEMM (bf16 MFMA, BK=32, global_load_lds, no fences)
// blocks [0,224):   q, 128x128 tile, split-K=8 -> fp32 qsl[s][896][512]
// blocks [224,736): kv, 128x64 tile, full K -> bf16 KBF scatter; n0==0 tiles
//                   also compute vp via WVPT B-fragment (cols 0..7)
// ---------------------------------------------------------------------------
__global__ __launch_bounds__(256)
void proj_kernel(const __bf16* __restrict__ ANQ, const __bf16* __restrict__ WQT,
                 const __bf16* __restrict__ ANKV, const __bf16* __restrict__ WKT,
                 const __bf16* __restrict__ WVPT,
                 float* __restrict__ qsl, __bf16* __restrict__ kout,
                 float* __restrict__ vpm) {
    __shared__ __align__(16) __bf16 As[128 * 32];
    __shared__ __align__(16) __bf16 Bs[128 * 32];
    int b = blockIdx.x;
    int tid = threadIdx.x;
    int lane = tid & 63, w = tid >> 6;
    int n16 = lane & 15, quad = lane >> 4;
    const f32x4 z = {0.f, 0.f, 0.f, 0.f};

    if (b < 224) {
        // ---------------- q path: 128x128, split-K=8 ----------------
        int slice = b / 28, tile = b % 28;
        long long m0 = (long long)(tile % 7) * 128;
        long long n0 = (long long)(tile / 7) * 128;
        int kbeg = slice * 384, kend = kbeg + 384;
        int wr = (w >> 1) * 64, wc = (w & 1) * 64;
        const __bf16* aG = ANQ + (m0 + (tid >> 2)) * DH + (tid & 3) * 8;
        const __bf16* bG = WQT + (n0 + (tid >> 2)) * DH + (tid & 3) * 8;
        __bf16* aL = As + tid * 8;
        __bf16* bL = Bs + tid * 8;
        f32x4 acc[4][4];
        #pragma unroll
        for (int i = 0; i < 4; ++i)
            #pragma unroll
            for (int j = 0; j < 4; ++j) acc[i][j] = z;
        for (int k0 = kbeg; k0 < kend; k0 += 32) {
            async_copy16(aG + k0, aL);
            async_copy16(aG + (long long)64 * DH + k0, aL + 2048);
            async_copy16(bG + k0, bL);
            async_copy16(bG + (long long)64 * DH + k0, bL + 2048);
            __syncthreads();
            bf16x8 af[4], bfr[4];
            #pragma unroll
            for (int i = 0; i < 4; ++i)
                af[i]  = *(const bf16x8*)&As[(wr + i * 16 + n16) * 32 + quad * 8];
            #pragma unroll
            for (int j = 0; j < 4; ++j)
                bfr[j] = *(const bf16x8*)&Bs[(wc + j * 16 + n16) * 32 + quad * 8];
            #pragma unroll
            for (int i = 0; i < 4; ++i)
                #pragma unroll
                for (int j = 0; j < 4; ++j)
                    acc[i][j] = __builtin_amdgcn_mfma_f32_16x16x32_bf16(af[i], bfr[j], acc[i][j], 0, 0, 0);
            __syncthreads();
        }
        float* dst = qsl + (long long)slice * (N_SEQ * INNER);
        #pragma unroll
        for (int i = 0; i < 4; ++i)
            #pragma unroll
            for (int r = 0; r < 4; ++r) {
                long long gr = m0 + wr + i * 16 + quad * 4 + r;
                #pragma unroll
                for (int j = 0; j < 4; ++j)
                    dst[gr * INNER + n0 + wc + j * 16 + n16] = acc[i][j][r];
            }
    } else {
        // ---------------- kv path: 128x64 tile, full K=1024 ----------------
        int b2 = b - 224;
        long long m0 = (long long)(b2 >> 3) * 128;
        long long n0 = (long long)(b2 & 7) * 64;
        int wr = (w >> 1) * 64, wc = (w & 1) * 32;
        bool dovp = (n0 == 0) && ((w & 1) == 0);
        const __bf16* aG = ANKV + (m0 + (tid >> 2)) * DC + (tid & 3) * 8;
        const __bf16* bG = WKT  + (n0 + (tid >> 2)) * DC + (tid & 3) * 8;
        __bf16* aL = As + tid * 8;
        __bf16* bL = Bs + tid * 8;
        f32x4 acc[4][2], accv[4];
        #pragma unroll
        for (int i = 0; i < 4; ++i) {
            accv[i] = z;
            acc[i][0] = z; acc[i][1] = z;
        }
        for (int k0 = 0; k0 < DC; k0 += 32) {
            async_copy16(aG + k0, aL);
            async_copy16(aG + (long long)64 * DC + k0, aL + 2048);
            async_copy16(bG + k0, bL);
            bf16x8 bv;
            if (dovp) bv = *(const bf16x8*)&WVPT[n16 * 1024 + k0 + quad * 8];
            __syncthreads();
            bf16x8 af[4], bfr[2];
            #pragma unroll
            for (int i = 0; i < 4; ++i)
                af[i]  = *(const bf16x8*)&As[(wr + i * 16 + n16) * 32 + quad * 8];
            #pragma unroll
            for (int j = 0; j < 2; ++j)
                bfr[j] = *(const bf16x8*)&Bs[(wc + j * 16 + n16) * 32 + quad * 8];
            #pragma unroll
            for (int i = 0; i < 4; ++i) {
                acc[i][0] = __builtin_amdgcn_mfma_f32_16x16x32_bf16(af[i], bfr[0], acc[i][0], 0, 0, 0);
                acc[i][1] = __builtin_amdgcn_mfma_f32_16x16x32_bf16(af[i], bfr[1], acc[i][1], 0, 0, 0);
            }
            if (dovp) {
                #pragma unroll
                for (int i = 0; i < 4; ++i)
                    accv[i] = __builtin_amdgcn_mfma_f32_16x16x32_bf16(af[i], bv, accv[i], 0, 0, 0);
            }
            __syncthreads();
        }
        #pragma unroll
        for (int i = 0; i < 4; ++i)
            #pragma unroll
            for (int r = 0; r < 4; ++r) {
                long long gr = m0 + wr + i * 16 + quad * 4 + r;
                if (gr >= MKV) continue;
                int cc = (int)(gr / JLEN), jj = (int)(gr % JLEN);
                #pragma unroll
                for (int j = 0; j < 2; ++j) {
                    long long gc = n0 + wc + j * 16 + n16;
                    kout[((long long)(cc * 128) + jj + 1) * INNER + gc] = (__bf16)acc[i][j][r];
                }
                if (dovp && n16 < 8) vpm[gr * 8 + n16] = accv[i][r];
            }
    }
}

// ---------------------------------------------------------------------------
// K4: reduce 8 q split-K slices -> bf16 (float4 per thread)
// ---------------------------------------------------------------------------
__global__ void qreduce_kernel(const float* __restrict__ qsl, __bf16* __restrict__ qbf) {
    int t4 = blockIdx.x * 256 + threadIdx.x;   // 114688 float4 chunks
    const int SL = N_SEQ * INNER / 4;
    float4 s = {0.f, 0.f, 0.f, 0.f};
    #pragma unroll
    for (int k = 0; k < 8; ++k) {
        float4 v = ((const float4*)qsl)[(long long)k * SL + t4];
        s.x += v.x; s.y += v.y; s.z += v.z; s.w += v.w;
    }
    __bf16 ov[4] = {(__bf16)s.x, (__bf16)s.y, (__bf16)s.z, (__bf16)s.w};
    ((ushort4*)qbf)[t4] = *(ushort4*)ov;
}

// ---------------------------------------------------------------------------
// K5: attention via MFMA. grid (7, NCTX*HEADS). K-head tile staged into LDS.
// ---------------------------------------------------------------------------
#define KROW 72   // LDS row stride in bf16 (64 data + 8 pad)

__global__ __launch_bounds__(256)
void attn_mfma_kernel(const __bf16* __restrict__ qb, const __bf16* __restrict__ kb,
                      const float* __restrict__ vpm, const float* __restrict__ vpnull,
                      const int* __restrict__ mask, float* __restrict__ s_buf) {
    __shared__ __align__(16) __bf16 ksh[128 * KROW];
    __shared__ float vpsh[128];
    __shared__ float amsh[128];
    int ch = blockIdx.y;
    int h = ch & 7, c = ch >> 3;
    int tid = threadIdx.x;
    int lane = tid & 63, w = tid >> 6;
    int n16 = lane & 15, quad = lane >> 4;

    const __bf16* kbase = kb + (long long)(c * 128) * INNER + h * DHEAD;
    #pragma unroll
    for (int p = 0; p < 4; ++p) {
        int chunk = tid + p * 256;
        int row = chunk >> 3, o = chunk & 7;
        bf16x8 v = *(const bf16x8*)(kbase + (long long)row * INNER + o * 8);
        *(bf16x8*)&ksh[row * KROW + o * 8] = v;
    }
    if (tid < 128) {
        vpsh[tid] = (tid == 0) ? vpnull[h] : vpm[(long long)(c * JLEN + tid - 1) * 8 + h];
        amsh[tid] = (tid == 0) ? 0.f : (mask[tid - 1] ? 0.f : -3.0e38f);
    }
    __syncthreads();

    bf16x8 bF[8][2];
    #pragma unroll
    for (int t = 0; t < 8; ++t)
        #pragma unroll
        for (int s = 0; s < 2; ++s)
            bF[t][s] = *(const bf16x8*)&ksh[(t * 16 + n16) * KROW + s * 32 + quad * 8];

    float vpv[8], am[8];
    #pragma unroll
    for (int t = 0; t < 8; ++t) {
        vpv[t] = vpsh[t * 16 + n16];
        am[t]  = amsh[t * 16 + n16];
    }

    const __bf16* qbase = qb + h * DHEAD;
    bf16x8 aF[2][2];
    int r0s[2];
    #pragma unroll
    for (int it2 = 0; it2 < 2; ++it2) {
        int tile = blockIdx.x * 8 + it2 * 4 + w;
        r0s[it2] = tile * 16;
        const __bf16* qrow = qbase + (long long)(r0s[it2] + n16) * INNER + quad * 8;
        aF[it2][0] = *(const bf16x8*)(qrow);
        aF[it2][1] = *(const bf16x8*)(qrow + 32);
    }

    const f32x4 zero = {0.f, 0.f, 0.f, 0.f};
    #pragma unroll
    for (int it2 = 0; it2 < 2; ++it2) {
        int r0 = r0s[it2];
        f32x4 acc[8];
        #pragma unroll
        for (int t = 0; t < 8; ++t) {
            acc[t] = __builtin_amdgcn_mfma_f32_16x16x32_bf16(aF[it2][0], bF[t][0], zero,   0, 0, 0);
            acc[t] = __builtin_amdgcn_mfma_f32_16x16x32_bf16(aF[it2][1], bF[t][1], acc[t], 0, 0, 0);
        }
        float mloc = -3.0e38f;
        #pragma unroll
        for (int t = 0; t < 8; ++t)
            #pragma unroll
            for (int r = 0; r < 4; ++r)
                mloc = fmaxf(mloc, acc[t][r] * 0.125f + am[t]);
        #pragma unroll
        for (int o = 1; o < 16; o <<= 1) mloc = fmaxf(mloc, __shfl_xor(mloc, o, 16));
        float lr[4] = {0.f, 0.f, 0.f, 0.f}, pr[4] = {0.f, 0.f, 0.f, 0.f};
        #pragma unroll
        for (int t = 0; t < 8; ++t) {
            #pragma unroll
            for (int r = 0; r < 4; ++r) {
                float e = __expf(acc[t][r] * 0.125f + am[t] - mloc);
                lr[r] += e; pr[r] += e * vpv[t];
            }
        }
        #pragma unroll
        for (int o = 1; o < 16; o <<= 1) {
            #pragma unroll
            for (int r = 0; r < 4; ++r) {
                lr[r] += __shfl_xor(lr[r], o, 16);
                pr[r] += __shfl_xor(pr[r], o, 16);
            }
        }
        if (n16 == 0) {
            #pragma unroll
            for (int r = 0; r < 4; ++r)
                s_buf[(long long)ch * N_SEQ + r0 + quad * 4 + r] = pr[r] / lr[r];
        }
    }
}

// ---------------------------------------------------------------------------
// K6: final: pred[n,c] = softplus(e_dot[n] + sum_h s[c,h,n] + bop + bp)
// ---------------------------------------------------------------------------
__global__ void final_kernel(const float* __restrict__ s_buf,
                             const float* __restrict__ e_dot,
                             const float* __restrict__ bop,
                             const float* __restrict__ bp,
                             float* __restrict__ out) {
    int t = blockIdx.x * blockDim.x + threadIdx.x;
    if (t >= N_SEQ * NCTX) return;
    int n = t >> 6, c = t & 63;
    float s = 0.f;
    #pragma unroll
    for (int h = 0; h < HEADS; ++h) s += s_buf[((long long)(c * HEADS + h)) * N_SEQ + n];
    float x = e_dot[n] + s + *bop + *bp;
    out[t] = fmaxf(x, 0.f) + log1pf(__expf(-fabsf(x)));
}

// ---------------------------------------------------------------------------
extern "C" void kernel_launch(void* const* d_in, const int* in_sizes, int n_in,
                              void* d_out, int out_size, void* d_ws, size_t ws_size,
                              hipStream_t stream) {
    const float* emb   = (const float*)d_in[0];
    const float* ctx   = (const float*)d_in[1];
    const int*   cmask = (const int*)  d_in[2];
    const float* qg    = (const float*)d_in[3];
    const float* qb_   = (const float*)d_in[4];
    const float* kvg   = (const float*)d_in[5];
    const float* kvb   = (const float*)d_in[6];
    const float* Wq    = (const float*)d_in[7];
    const float* Wkv   = (const float*)d_in[8];
    const float* nullk = (const float*)d_in[9];
    const float* nullv = (const float*)d_in[10];
    const float* Wo    = (const float*)d_in[11];
    const float* bo    = (const float*)d_in[12];
    const float* Wp    = (const float*)d_in[13];
    const float* bp    = (const float*)d_in[14];
    float* out  = (float*)d_out;
    float* ws_f = (float*)d_ws;

    float*  EDOT   = ws_f + OFF_EDOT;
    __bf16* QBF    = (__bf16*)(ws_f + OFF_QBF);
    __bf16* KBF    = (__bf16*)(ws_f + OFF_KBF);
    float*  VPM    = ws_f + OFF_VPM;
    float*  VPNULL = ws_f + OFF_VPNULL;
    float*  WOP    = ws_f + OFF_WOP;
    float*  BOP    = ws_f + OFF_BOP;
    float*  SBUF   = ws_f + OFF_SBUF;
    __bf16* ANQ    = (__bf16*)(ws_f + OFF_ANQ);
    __bf16* ANKV   = (__bf16*)(ws_f + OFF_ANKV);
    __bf16* WQT    = (__bf16*)(ws_f + OFF_WQT);
    __bf16* WKT    = (__bf16*)(ws_f + OFF_WKT);
    __bf16* WVPT   = (__bf16*)(ws_f + OFF_WVPT);
    float*  QSL    = ws_f + OFF_QSL;

    ln_wop_kernel<<<N_SEQ + MKV + INNER + 1, 256, 0, stream>>>(
        emb, ctx, qg, qb_, kvg, kvb, Wp, Wo, bo, ANQ, ANKV, EDOT, WOP, BOP);
    prep2_kernel<<<2081, 256, 0, stream>>>(
        Wq, Wkv, WOP, nullv, nullk, WQT, WKT, WVPT, VPNULL, KBF);
    proj_kernel<<<736, 256, 0, stream>>>(
        ANQ, WQT, ANKV, WKT, WVPT, QSL, KBF, VPM);
    qreduce_kernel<<<(N_SEQ * INNER / 4) / 256, 256, 0, stream>>>(QSL, QBF);
    attn_mfma_kernel<<<dim3(7, NCTX * HEADS), 256, 0, stream>>>(
        QBF, KBF, VPM, VPNULL, cmask, SBUF);
    final_kernel<<<(N_SEQ * NCTX + 255) / 256, 256, 0, stream>>>(SBUF, EDOT, BOP, bp, out);
}

// Round 11
// 217.377 us; speedup vs baseline: 1.7695x; 1.0155x over previous
//
#include <hip/hip_runtime.h>
#include <math.h>

// ---------------------------------------------------------------------------
// Problem constants
// ---------------------------------------------------------------------------
#define N_SEQ   896
#define DH      3072
#define NCTX    64
#define JLEN    127
#define DC      1024
#define HEADS   8
#define DHEAD   64
#define INNER   512   // HEADS*DHEAD
#define MKV     8128  // NCTX*JLEN
#define MKVPAD  8192

typedef __bf16 bf16x8 __attribute__((ext_vector_type(8)));
typedef float  f32x4  __attribute__((ext_vector_type(4)));

// workspace float offsets
#define OFF_EDOT   0LL
#define OFF_QBF    (OFF_EDOT + N_SEQ)
#define OFF_KBF    (OFF_QBF  + (long long)N_SEQ*INNER/2)     // bf16 896x512
#define OFF_VPM    (OFF_KBF  + (long long)NCTX*128*INNER/2)  // fp32 8128x8
#define OFF_VPNULL (OFF_VPM  + (long long)MKV*8)
#define OFF_WOP    (OFF_VPNULL + 8)
#define OFF_BOP    (OFF_WOP  + INNER)
#define OFF_SBUF   (OFF_BOP  + 16)                           // fp32 64*8*896
#define OFF_ANQ    (OFF_SBUF + (long long)NCTX*HEADS*N_SEQ)  // bf16 896x3072
#define OFF_ANKV   (OFF_ANQ  + (long long)N_SEQ*DH/2)        // bf16 8192x1024
#define OFF_WQT    (OFF_ANKV + (long long)MKVPAD*DC/2)       // bf16 512x3072
#define OFF_WKT    (OFF_WQT  + (long long)INNER*DH/2)        // bf16 512x1024
#define OFF_WVPT   (OFF_WKT  + (long long)INNER*DC/2)        // bf16 16x1024
#define OFF_QSL    (OFF_WVPT + 16*1024/2)                    // fp32 8 x 896x512

// ---------------------------------------------------------------------------
// async global->LDS 16B helper
// ---------------------------------------------------------------------------
__device__ __forceinline__ void async_copy16(const __bf16* g, __bf16* l) {
    __builtin_amdgcn_global_load_lds(
        (const __attribute__((address_space(1))) unsigned int*)g,
        (__attribute__((address_space(3))) unsigned int*)l,
        16, 0, 0);
}

// ---------------------------------------------------------------------------
// LN row helper (block-per-row, proven): stats + normalize + bf16 convert
// ---------------------------------------------------------------------------
template <int P>
__device__ __forceinline__
void ln_row(const float* __restrict__ x,
            const float* __restrict__ gamma, const float* __restrict__ beta,
            const float* __restrict__ wp,
            __bf16* __restrict__ o, float* __restrict__ dotout) {
    const int K = P * 1024;
    float4 xv[P];
    float s = 0.f, ss = 0.f, dp = 0.f;
    #pragma unroll
    for (int p = 0; p < P; ++p) {
        xv[p] = *(const float4*)&x[p * 1024 + threadIdx.x * 4];
        s  += xv[p].x + xv[p].y + xv[p].z + xv[p].w;
        ss += xv[p].x * xv[p].x + xv[p].y * xv[p].y
            + xv[p].z * xv[p].z + xv[p].w * xv[p].w;
        if (wp) {
            float4 w4 = *(const float4*)&wp[p * 1024 + threadIdx.x * 4];
            dp += xv[p].x * w4.x + xv[p].y * w4.y + xv[p].z * w4.z + xv[p].w * w4.w;
        }
    }
    #pragma unroll
    for (int ofs = 32; ofs > 0; ofs >>= 1) {
        s  += __shfl_down(s,  ofs);
        ss += __shfl_down(ss, ofs);
        dp += __shfl_down(dp, ofs);
    }
    __shared__ float red[3][4];
    __shared__ float sh_mu, sh_rstd;
    int lane = threadIdx.x & 63, w = threadIdx.x >> 6;
    if (lane == 0) { red[0][w] = s; red[1][w] = ss; red[2][w] = dp; }
    __syncthreads();
    if (threadIdx.x == 0) {
        float S  = red[0][0] + red[0][1] + red[0][2] + red[0][3];
        float SS = red[1][0] + red[1][1] + red[1][2] + red[1][3];
        float m = S / K;
        sh_mu = m;
        sh_rstd = rsqrtf(SS / K - m * m + 1e-5f);
        if (dotout) *dotout = red[2][0] + red[2][1] + red[2][2] + red[2][3];
    }
    __syncthreads();
    float m = sh_mu, r = sh_rstd;
    #pragma unroll
    for (int p = 0; p < P; ++p) {
        int col = p * 1024 + threadIdx.x * 4;
        float4 g4 = *(const float4*)&gamma[col];
        float4 b4 = *(const float4*)&beta[col];
        __bf16 ov[4];
        ov[0] = (__bf16)((xv[p].x - m) * r * g4.x + b4.x);
        ov[1] = (__bf16)((xv[p].y - m) * r * g4.y + b4.y);
        ov[2] = (__bf16)((xv[p].z - m) * r * g4.z + b4.z);
        ov[3] = (__bf16)((xv[p].w - m) * r * g4.w + b4.w);
        *(ushort4*)&o[col] = *(ushort4*)ov;
    }
}

// ---------------------------------------------------------------------------
// K1: fused ln_q (896) + ln_kv (8128) + wop/bop (513) by block range
// ---------------------------------------------------------------------------
__global__ __launch_bounds__(256)
void ln_wop_kernel(const float* __restrict__ emb, const float* __restrict__ ctx,
                   const float* __restrict__ qg, const float* __restrict__ qb,
                   const float* __restrict__ kvg, const float* __restrict__ kvb,
                   const float* __restrict__ Wp, const float* __restrict__ Wo,
                   const float* __restrict__ bo,
                   __bf16* __restrict__ anq, __bf16* __restrict__ ankv,
                   float* __restrict__ edot, float* __restrict__ wop,
                   float* __restrict__ bop) {
    int b = blockIdx.x;
    if (b < N_SEQ) {
        ln_row<3>(emb + (long long)b * DH, qg, qb, Wp,
                  anq + (long long)b * DH, edot + b);
    } else if (b < N_SEQ + MKV) {
        int r = b - N_SEQ;
        ln_row<1>(ctx + (long long)r * DC, kvg, kvb, nullptr,
                  ankv + (long long)r * DC, nullptr);
    } else {
        int r = b - (N_SEQ + MKV);   // 0..512
        const float* src = (r < INNER) ? (Wo + (long long)r * DH) : bo;
        float s = 0.f;
        for (int k = threadIdx.x; k < DH; k += 256) s += src[k] * Wp[k];
        #pragma unroll
        for (int o = 32; o > 0; o >>= 1) s += __shfl_down(s, o);
        __shared__ float red2[4];
        int lane = threadIdx.x & 63, w = threadIdx.x >> 6;
        if (lane == 0) red2[w] = s;
        __syncthreads();
        if (threadIdx.x == 0) {
            float S = red2[0] + red2[1] + red2[2] + red2[3];
            if (r < INNER) wop[r] = S; else *bop = S;
        }
    }
}

// ---------------------------------------------------------------------------
// K2: fused weight prep: WQT transpose (1536) + WKT transpose (512) +
//     wvpt (32) + null_k/vpnull/zero (1)
// ---------------------------------------------------------------------------
__device__ __forceinline__
void transpose_tile(const float* __restrict__ src, int srcStride,
                    __bf16* __restrict__ dst, int dstStride,
                    int rb, int cb, float t[32][33]) {
    int tx = threadIdx.x & 31, ty = threadIdx.x >> 5;
    #pragma unroll
    for (int i = 0; i < 32; i += 8)
        t[ty + i][tx] = src[(long long)(rb + ty + i) * srcStride + cb + tx];
    __syncthreads();
    #pragma unroll
    for (int i = 0; i < 32; i += 8)
        dst[(long long)(cb + ty + i) * dstStride + rb + tx] = (__bf16)t[tx][ty + i];
}

__global__ __launch_bounds__(256)
void prep2_kernel(const float* __restrict__ Wq, const float* __restrict__ Wkv,
                  const float* __restrict__ wop,
                  const float* __restrict__ null_v, const float* __restrict__ null_k,
                  __bf16* __restrict__ wqt, __bf16* __restrict__ wkt,
                  __bf16* __restrict__ wvpt, float* __restrict__ vpnull,
                  __bf16* __restrict__ k_bf) {
    __shared__ float t[32][33];
    int b = blockIdx.x;
    if (b < 1536) {
        int rb = (b >> 4) * 32, cb = (b & 15) * 32;
        transpose_tile(Wq, INNER, wqt, DH, rb, cb, t);
    } else if (b < 2048) {
        int bi = b - 1536;
        int rb = (bi >> 4) * 32, cb = (bi & 15) * 32;
        transpose_tile(Wkv, 2 * INNER, wkt, DC, rb, cb, t);
    } else if (b < 2080) {
        int tt = (b - 2048) * 256 + threadIdx.x;   // 0..8191
        int k = tt >> 3, h = tt & 7;
        const float* src = Wkv + (long long)k * (2 * INNER) + INNER + h * 64;
        const float* wv  = wop + h * 64;
        float s = 0.f;
        #pragma unroll 16
        for (int d = 0; d < 64; ++d) s += src[d] * wv[d];
        wvpt[h * 1024 + k] = (__bf16)s;
    } else {
        for (int i = threadIdx.x; i < 8 * 1024; i += 256)
            wvpt[8 * 1024 + i] = (__bf16)0.f;
        for (int i = threadIdx.x; i < NCTX * INNER; i += 256) {
            int c = i >> 9, d = i & 511;
            k_bf[(long long)(c * 128) * INNER + d] = (__bf16)null_k[d];
        }
        if (threadIdx.x < 8) {
            int h = threadIdx.x;
            float s = 0.f;
            #pragma unroll 16
            for (int d = 0; d < 64; ++d) s += null_v[h * 64 + d] * wop[h * 64 + d];
            vpnull[h] = s;
        }
    }
}

// ---------------------------------------------------------------------------
// K3: merged projection GEMM (bf16 MFMA, BK=32, global_load_lds, no fences)
// blocks [0,224):   q, 128x128 tile, split-K=8 -> fp32 qsl[s][896][512]
//                   b = m*32 + slice*4 + n  (B-tile sharers spaced 32 -> same XCD)
// blocks [224,736): kv, 128x64 tile, full K -> bf16 KBF scatter
//                   m0 = (b2&63)*128, n0 = (b2>>6)*64 (A-tile sharers spaced 64
//                   -> same XCD, L2 absorbs the 8x A re-read); n0==0 tiles also
//                   compute vp via WVPT B-fragment (cols 0..7)
// ---------------------------------------------------------------------------
__global__ __launch_bounds__(256)
void proj_kernel(const __bf16* __restrict__ ANQ, const __bf16* __restrict__ WQT,
                 const __bf16* __restrict__ ANKV, const __bf16* __restrict__ WKT,
                 const __bf16* __restrict__ WVPT,
                 float* __restrict__ qsl, __bf16* __restrict__ kout,
                 float* __restrict__ vpm) {
    __shared__ __align__(16) __bf16 As[128 * 32];
    __shared__ __align__(16) __bf16 Bs[128 * 32];
    int b = blockIdx.x;
    int tid = threadIdx.x;
    int lane = tid & 63, w = tid >> 6;
    int n16 = lane & 15, quad = lane >> 4;
    const f32x4 z = {0.f, 0.f, 0.f, 0.f};

    if (b < 224) {
        // ---------------- q path: 128x128, split-K=8 ----------------
        int m = b >> 5;              // 0..6
        int rem = b & 31;
        int slice = rem >> 2;        // 0..7
        int n = rem & 3;             // 0..3
        long long m0 = (long long)m * 128;
        long long n0 = (long long)n * 128;
        int kbeg = slice * 384, kend = kbeg + 384;
        int wr = (w >> 1) * 64, wc = (w & 1) * 64;
        const __bf16* aG = ANQ + (m0 + (tid >> 2)) * DH + (tid & 3) * 8;
        const __bf16* bG = WQT + (n0 + (tid >> 2)) * DH + (tid & 3) * 8;
        __bf16* aL = As + tid * 8;
        __bf16* bL = Bs + tid * 8;
        f32x4 acc[4][4];
        #pragma unroll
        for (int i = 0; i < 4; ++i)
            #pragma unroll
            for (int j = 0; j < 4; ++j) acc[i][j] = z;
        for (int k0 = kbeg; k0 < kend; k0 += 32) {
            async_copy16(aG + k0, aL);
            async_copy16(aG + (long long)64 * DH + k0, aL + 2048);
            async_copy16(bG + k0, bL);
            async_copy16(bG + (long long)64 * DH + k0, bL + 2048);
            __syncthreads();
            bf16x8 af[4], bfr[4];
            #pragma unroll
            for (int i = 0; i < 4; ++i)
                af[i]  = *(const bf16x8*)&As[(wr + i * 16 + n16) * 32 + quad * 8];
            #pragma unroll
            for (int j = 0; j < 4; ++j)
                bfr[j] = *(const bf16x8*)&Bs[(wc + j * 16 + n16) * 32 + quad * 8];
            #pragma unroll
            for (int i = 0; i < 4; ++i)
                #pragma unroll
                for (int j = 0; j < 4; ++j)
                    acc[i][j] = __builtin_amdgcn_mfma_f32_16x16x32_bf16(af[i], bfr[j], acc[i][j], 0, 0, 0);
            __syncthreads();
        }
        float* dst = qsl + (long long)slice * (N_SEQ * INNER);
        #pragma unroll
        for (int i = 0; i < 4; ++i)
            #pragma unroll
            for (int r = 0; r < 4; ++r) {
                long long gr = m0 + wr + i * 16 + quad * 4 + r;
                #pragma unroll
                for (int j = 0; j < 4; ++j)
                    dst[gr * INNER + n0 + wc + j * 16 + n16] = acc[i][j][r];
            }
    } else {
        // ---------------- kv path: 128x64 tile, full K=1024 ----------------
        int b2 = b - 224;
        long long m0 = (long long)(b2 & 63) * 128;
        long long n0 = (long long)(b2 >> 6) * 64;
        int wr = (w >> 1) * 64, wc = (w & 1) * 32;
        bool dovp = (n0 == 0) && ((w & 1) == 0);
        const __bf16* aG = ANKV + (m0 + (tid >> 2)) * DC + (tid & 3) * 8;
        const __bf16* bG = WKT  + (n0 + (tid >> 2)) * DC + (tid & 3) * 8;
        __bf16* aL = As + tid * 8;
        __bf16* bL = Bs + tid * 8;
        f32x4 acc[4][2], accv[4];
        #pragma unroll
        for (int i = 0; i < 4; ++i) {
            accv[i] = z;
            acc[i][0] = z; acc[i][1] = z;
        }
        for (int k0 = 0; k0 < DC; k0 += 32) {
            async_copy16(aG + k0, aL);
            async_copy16(aG + (long long)64 * DC + k0, aL + 2048);
            async_copy16(bG + k0, bL);
            bf16x8 bv;
            if (dovp) bv = *(const bf16x8*)&WVPT[n16 * 1024 + k0 + quad * 8];
            __syncthreads();
            bf16x8 af[4], bfr[2];
            #pragma unroll
            for (int i = 0; i < 4; ++i)
                af[i]  = *(const bf16x8*)&As[(wr + i * 16 + n16) * 32 + quad * 8];
            #pragma unroll
            for (int j = 0; j < 2; ++j)
                bfr[j] = *(const bf16x8*)&Bs[(wc + j * 16 + n16) * 32 + quad * 8];
            #pragma unroll
            for (int i = 0; i < 4; ++i) {
                acc[i][0] = __builtin_amdgcn_mfma_f32_16x16x32_bf16(af[i], bfr[0], acc[i][0], 0, 0, 0);
                acc[i][1] = __builtin_amdgcn_mfma_f32_16x16x32_bf16(af[i], bfr[1], acc[i][1], 0, 0, 0);
            }
            if (dovp) {
                #pragma unroll
                for (int i = 0; i < 4; ++i)
                    accv[i] = __builtin_amdgcn_mfma_f32_16x16x32_bf16(af[i], bv, accv[i], 0, 0, 0);
            }
            __syncthreads();
        }
        #pragma unroll
        for (int i = 0; i < 4; ++i)
            #pragma unroll
            for (int r = 0; r < 4; ++r) {
                long long gr = m0 + wr + i * 16 + quad * 4 + r;
                if (gr >= MKV) continue;
                int cc = (int)(gr / JLEN), jj = (int)(gr % JLEN);
                #pragma unroll
                for (int j = 0; j < 2; ++j) {
                    long long gc = n0 + wc + j * 16 + n16;
                    kout[((long long)(cc * 128) + jj + 1) * INNER + gc] = (__bf16)acc[i][j][r];
                }
                if (dovp && n16 < 8) vpm[gr * 8 + n16] = accv[i][r];
            }
    }
}

// ---------------------------------------------------------------------------
// K4: reduce 8 q split-K slices -> bf16 (float4 per thread)
// ---------------------------------------------------------------------------
__global__ void qreduce_kernel(const float* __restrict__ qsl, __bf16* __restrict__ qbf) {
    int t4 = blockIdx.x * 256 + threadIdx.x;   // 114688 float4 chunks
    const int SL = N_SEQ * INNER / 4;
    float4 s = {0.f, 0.f, 0.f, 0.f};
    #pragma unroll
    for (int k = 0; k < 8; ++k) {
        float4 v = ((const float4*)qsl)[(long long)k * SL + t4];
        s.x += v.x; s.y += v.y; s.z += v.z; s.w += v.w;
    }
    __bf16 ov[4] = {(__bf16)s.x, (__bf16)s.y, (__bf16)s.z, (__bf16)s.w};
    ((ushort4*)qbf)[t4] = *(ushort4*)ov;
}

// ---------------------------------------------------------------------------
// K5: attention via MFMA. grid (7, NCTX*HEADS). K-head tile staged into LDS.
// ---------------------------------------------------------------------------
#define KROW 72   // LDS row stride in bf16 (64 data + 8 pad)

__global__ __launch_bounds__(256)
void attn_mfma_kernel(const __bf16* __restrict__ qb, const __bf16* __restrict__ kb,
                      const float* __restrict__ vpm, const float* __restrict__ vpnull,
                      const int* __restrict__ mask, float* __restrict__ s_buf) {
    __shared__ __align__(16) __bf16 ksh[128 * KROW];
    __shared__ float vpsh[128];
    __shared__ float amsh[128];
    int ch = blockIdx.y;
    int h = ch & 7, c = ch >> 3;
    int tid = threadIdx.x;
    int lane = tid & 63, w = tid >> 6;
    int n16 = lane & 15, quad = lane >> 4;

    const __bf16* kbase = kb + (long long)(c * 128) * INNER + h * DHEAD;
    #pragma unroll
    for (int p = 0; p < 4; ++p) {
        int chunk = tid + p * 256;
        int row = chunk >> 3, o = chunk & 7;
        bf16x8 v = *(const bf16x8*)(kbase + (long long)row * INNER + o * 8);
        *(bf16x8*)&ksh[row * KROW + o * 8] = v;
    }
    if (tid < 128) {
        vpsh[tid] = (tid == 0) ? vpnull[h] : vpm[(long long)(c * JLEN + tid - 1) * 8 + h];
        amsh[tid] = (tid == 0) ? 0.f : (mask[tid - 1] ? 0.f : -3.0e38f);
    }
    __syncthreads();

    bf16x8 bF[8][2];
    #pragma unroll
    for (int t = 0; t < 8; ++t)
        #pragma unroll
        for (int s = 0; s < 2; ++s)
            bF[t][s] = *(const bf16x8*)&ksh[(t * 16 + n16) * KROW + s * 32 + quad * 8];

    float vpv[8], am[8];
    #pragma unroll
    for (int t = 0; t < 8; ++t) {
        vpv[t] = vpsh[t * 16 + n16];
        am[t]  = amsh[t * 16 + n16];
    }

    const __bf16* qbase = qb + h * DHEAD;
    bf16x8 aF[2][2];
    int r0s[2];
    #pragma unroll
    for (int it2 = 0; it2 < 2; ++it2) {
        int tile = blockIdx.x * 8 + it2 * 4 + w;
        r0s[it2] = tile * 16;
        const __bf16* qrow = qbase + (long long)(r0s[it2] + n16) * INNER + quad * 8;
        aF[it2][0] = *(const bf16x8*)(qrow);
        aF[it2][1] = *(const bf16x8*)(qrow + 32);
    }

    const f32x4 zero = {0.f, 0.f, 0.f, 0.f};
    #pragma unroll
    for (int it2 = 0; it2 < 2; ++it2) {
        int r0 = r0s[it2];
        f32x4 acc[8];
        #pragma unroll
        for (int t = 0; t < 8; ++t) {
            acc[t] = __builtin_amdgcn_mfma_f32_16x16x32_bf16(aF[it2][0], bF[t][0], zero,   0, 0, 0);
            acc[t] = __builtin_amdgcn_mfma_f32_16x16x32_bf16(aF[it2][1], bF[t][1], acc[t], 0, 0, 0);
        }
        float mloc = -3.0e38f;
        #pragma unroll
        for (int t = 0; t < 8; ++t)
            #pragma unroll
            for (int r = 0; r < 4; ++r)
                mloc = fmaxf(mloc, acc[t][r] * 0.125f + am[t]);
        #pragma unroll
        for (int o = 1; o < 16; o <<= 1) mloc = fmaxf(mloc, __shfl_xor(mloc, o, 16));
        float lr[4] = {0.f, 0.f, 0.f, 0.f}, pr[4] = {0.f, 0.f, 0.f, 0.f};
        #pragma unroll
        for (int t = 0; t < 8; ++t) {
            #pragma unroll
            for (int r = 0; r < 4; ++r) {
                float e = __expf(acc[t][r] * 0.125f + am[t] - mloc);
                lr[r] += e; pr[r] += e * vpv[t];
            }
        }
        #pragma unroll
        for (int o = 1; o < 16; o <<= 1) {
            #pragma unroll
            for (int r = 0; r < 4; ++r) {
                lr[r] += __shfl_xor(lr[r], o, 16);
                pr[r] += __shfl_xor(pr[r], o, 16);
            }
        }
        if (n16 == 0) {
            #pragma unroll
            for (int r = 0; r < 4; ++r)
                s_buf[(long long)ch * N_SEQ + r0 + quad * 4 + r] = pr[r] / lr[r];
        }
    }
}

// ---------------------------------------------------------------------------
// K6: final: pred[n,c] = softplus(e_dot[n] + sum_h s[c,h,n] + bop + bp)
// ---------------------------------------------------------------------------
__global__ void final_kernel(const float* __restrict__ s_buf,
                             const float* __restrict__ e_dot,
                             const float* __restrict__ bop,
                             const float* __restrict__ bp,
                             float* __restrict__ out) {
    int t = blockIdx.x * blockDim.x + threadIdx.x;
    if (t >= N_SEQ * NCTX) return;
    int n = t >> 6, c = t & 63;
    float s = 0.f;
    #pragma unroll
    for (int h = 0; h < HEADS; ++h) s += s_buf[((long long)(c * HEADS + h)) * N_SEQ + n];
    float x = e_dot[n] + s + *bop + *bp;
    out[t] = fmaxf(x, 0.f) + log1pf(__expf(-fabsf(x)));
}

// ---------------------------------------------------------------------------
extern "C" void kernel_launch(void* const* d_in, const int* in_sizes, int n_in,
                              void* d_out, int out_size, void* d_ws, size_t ws_size,
                              hipStream_t stream) {
    const float* emb   = (const float*)d_in[0];
    const float* ctx   = (const float*)d_in[1];
    const int*   cmask = (const int*)  d_in[2];
    const float* qg    = (const float*)d_in[3];
    const float* qb_   = (const float*)d_in[4];
    const float* kvg   = (const float*)d_in[5];
    const float* kvb   = (const float*)d_in[6];
    const float* Wq    = (const float*)d_in[7];
    const float* Wkv   = (const float*)d_in[8];
    const float* nullk = (const float*)d_in[9];
    const float* nullv = (const float*)d_in[10];
    const float* Wo    = (const float*)d_in[11];
    const float* bo    = (const float*)d_in[12];
    const float* Wp    = (const float*)d_in[13];
    const float* bp    = (const float*)d_in[14];
    float* out  = (float*)d_out;
    float* ws_f = (float*)d_ws;

    float*  EDOT   = ws_f + OFF_EDOT;
    __bf16* QBF    = (__bf16*)(ws_f + OFF_QBF);
    __bf16* KBF    = (__bf16*)(ws_f + OFF_KBF);
    float*  VPM    = ws_f + OFF_VPM;
    float*  VPNULL = ws_f + OFF_VPNULL;
    float*  WOP    = ws_f + OFF_WOP;
    float*  BOP    = ws_f + OFF_BOP;
    float*  SBUF   = ws_f + OFF_SBUF;
    __bf16* ANQ    = (__bf16*)(ws_f + OFF_ANQ);
    __bf16* ANKV   = (__bf16*)(ws_f + OFF_ANKV);
    __bf16* WQT    = (__bf16*)(ws_f + OFF_WQT);
    __bf16* WKT    = (__bf16*)(ws_f + OFF_WKT);
    __bf16* WVPT   = (__bf16*)(ws_f + OFF_WVPT);
    float*  QSL    = ws_f + OFF_QSL;

    ln_wop_kernel<<<N_SEQ + MKV + INNER + 1, 256, 0, stream>>>(
        emb, ctx, qg, qb_, kvg, kvb, Wp, Wo, bo, ANQ, ANKV, EDOT, WOP, BOP);
    prep2_kernel<<<2081, 256, 0, stream>>>(
        Wq, Wkv, WOP, nullv, nullk, WQT, WKT, WVPT, VPNULL, KBF);
    proj_kernel<<<736, 256, 0, stream>>>(
        ANQ, WQT, ANKV, WKT, WVPT, QSL, KBF, VPM);
    qreduce_kernel<<<(N_SEQ * INNER / 4) / 256, 256, 0, stream>>>(QSL, QBF);
    attn_mfma_kernel<<<dim3(7, NCTX * HEADS), 256, 0, stream>>>(
        QBF, KBF, VPM, VPNULL, cmask, SBUF);
    final_kernel<<<(N_SEQ * NCTX + 255) / 256, 256, 0, stream>>>(SBUF, EDOT, BOP, bp, out);
}